// Round 9
// baseline (177.734 us; speedup 1.0000x reference)
//
#include <hip/hip_runtime.h>

#define N_ITEMS 65536

// ---------------- Kernel 1: qpart[z] = x @ W (K-chunk 128 per z) ------------
__launch_bounds__(256)
__global__ void gemm_q_kernel(const float* __restrict__ A,
                              const float* __restrict__ W,
                              float* __restrict__ qpart) {
  __shared__ float As[16][132];
  __shared__ float Bs[16][132];
  const int tid = threadIdx.x;
  const int tx = tid & 15, ty = tid >> 4;
  const int rb = blockIdx.y * 128, cb = blockIdx.x * 128;
  const int kz = blockIdx.z * 128;
  const int ar = tid >> 2, ac = (tid & 3) << 2;
  const int bk = tid >> 5, bc = (tid & 31) << 2;

  float4 va0 = *(const float4*)&A[(rb + ar) * 1024 + kz + ac];
  float4 va1 = *(const float4*)&A[(rb + ar + 64) * 1024 + kz + ac];
  float4 vb0 = *(const float4*)&W[(kz + bk) * 1024 + cb + bc];
  float4 vb1 = *(const float4*)&W[(kz + bk + 8) * 1024 + cb + bc];

  float acc[8][8] = {};
  for (int k0 = 0; k0 < 128; k0 += 16) {
    As[ac + 0][ar] = va0.x; As[ac + 1][ar] = va0.y;
    As[ac + 2][ar] = va0.z; As[ac + 3][ar] = va0.w;
    As[ac + 0][ar + 64] = va1.x; As[ac + 1][ar + 64] = va1.y;
    As[ac + 2][ar + 64] = va1.z; As[ac + 3][ar + 64] = va1.w;
    *(float4*)&Bs[bk][bc] = vb0;
    *(float4*)&Bs[bk + 8][bc] = vb1;
    __syncthreads();
    if (k0 + 16 < 128) {
      va0 = *(const float4*)&A[(rb + ar) * 1024 + kz + k0 + 16 + ac];
      va1 = *(const float4*)&A[(rb + ar + 64) * 1024 + kz + k0 + 16 + ac];
      vb0 = *(const float4*)&W[(kz + k0 + 16 + bk) * 1024 + cb + bc];
      vb1 = *(const float4*)&W[(kz + k0 + 16 + bk + 8) * 1024 + cb + bc];
    }
#pragma unroll
    for (int kk = 0; kk < 16; kk++) {
      const float4 a0 = *(const float4*)&As[kk][ty << 2];
      const float4 a1 = *(const float4*)&As[kk][64 + (ty << 2)];
      const float4 b0 = *(const float4*)&Bs[kk][tx << 2];
      const float4 b1 = *(const float4*)&Bs[kk][64 + (tx << 2)];
      const float ar8[8] = {a0.x, a0.y, a0.z, a0.w, a1.x, a1.y, a1.z, a1.w};
      const float br8[8] = {b0.x, b0.y, b0.z, b0.w, b1.x, b1.y, b1.z, b1.w};
#pragma unroll
      for (int r = 0; r < 8; r++)
#pragma unroll
        for (int c = 0; c < 8; c++)
          acc[r][c] = fmaf(ar8[r], br8[c], acc[r][c]);
    }
    __syncthreads();
  }
  float* outp = qpart + blockIdx.z * 1048576;
#pragma unroll
  for (int rh = 0; rh < 2; rh++)
#pragma unroll
    for (int r = 0; r < 4; r++) {
      const int row = rb + rh * 64 + (ty << 2) + r;
      const int ri = rh * 4 + r;
      *(float4*)&outp[row * 1024 + cb + (tx << 2)] =
          make_float4(acc[ri][0], acc[ri][1], acc[ri][2], acc[ri][3]);
      *(float4*)&outp[row * 1024 + cb + 64 + (tx << 2)] =
          make_float4(acc[ri][4], acc[ri][5], acc[ri][6], acc[ri][7]);
    }
}

// ---------------- Kernel 1b: q = sum_z qpart[z] (pure BW) -------------------
__launch_bounds__(256)
__global__ void qsum_kernel(const float4* __restrict__ qp,
                            float4* __restrict__ q) {
  const int i = blockIdx.x * 256 + threadIdx.x;   // 0..131071
  float4 s0 = qp[i];
  float4 s1 = qp[i + 131072];
#pragma unroll
  for (int z = 1; z < 8; z++) {
    const float4 a = qp[z * 262144 + i];
    const float4 b = qp[z * 262144 + i + 131072];
    s0.x += a.x; s0.y += a.y; s0.z += a.z; s0.w += a.w;
    s1.x += b.x; s1.y += b.y; s1.z += b.z; s1.w += b.w;
  }
  q[i] = s0;
  q[i + 131072] = s1;
}

// ---------------- Kernel 2: lut + in-register qsq/csq + code packing ----------
// pack plane (i8 8-row b64 table): h = segment-local byte offset = c*64
// (entry stride = 8 replica qwords = 64 B; max 16320, fits u16).
__launch_bounds__(256)
__global__ void lut_kernel(const float* __restrict__ q,
                           const float* __restrict__ kcb,
                           const int* __restrict__ key_codes,
                           float* __restrict__ lut,
                           unsigned long long* __restrict__ pcodes,
                           uint4* __restrict__ poffs) {
  if (blockIdx.z == 8) {
    const int g0 = (((int)blockIdx.y * 4 + (int)blockIdx.x) * 256 + (int)threadIdx.x) * 4;
#pragma unroll
    for (int t = 0; t < 4; t++) {
      const int gid = g0 + t;
      unsigned long long p = 0ull;
      unsigned h[8];
#pragma unroll
      for (int j = 0; j < 8; j++) {
        const unsigned c = (unsigned)key_codes[gid * 8 + j] & 255u;
        p |= (unsigned long long)c << (8 * j);
        h[j] = c << 6;
      }
      pcodes[gid] = p;
      poffs[gid] = make_uint4(h[0] | (h[1] << 16), h[2] | (h[3] << 16),
                              h[4] | (h[5] << 16), h[6] | (h[7] << 16));
    }
    return;
  }

  __shared__ float As[32][68];
  __shared__ float Bs[32][68];
  const int tid = threadIdx.x;
  const int tx = tid & 15, ty = tid >> 4;
  const int m = blockIdx.z;
  const int rb = blockIdx.y * 64;
  const int cb0 = blockIdx.x * 64;
  float acc[4][4] = {};
  float qa[4] = {}, cs[4] = {};
  for (int k0 = 0; k0 < 128; k0 += 32) {
#pragma unroll
    for (int l = 0; l < 2; l++) {
      const int e = tid + l * 256;
      const int row = e >> 3, c4 = (e & 7) << 2;
      const float4 va = *(const float4*)&q[(rb + row) * 1024 + m * 128 + k0 + c4];
      As[c4 + 0][row] = va.x; As[c4 + 1][row] = va.y;
      As[c4 + 2][row] = va.z; As[c4 + 3][row] = va.w;
      const float4 vb = *(const float4*)&kcb[(m * 256 + cb0 + row) * 128 + k0 + c4];
      Bs[c4 + 0][row] = vb.x; Bs[c4 + 1][row] = vb.y;
      Bs[c4 + 2][row] = vb.z; Bs[c4 + 3][row] = vb.w;
    }
    __syncthreads();
#pragma unroll
    for (int kk = 0; kk < 32; kk++) {
      const float4 a = *(const float4*)&As[kk][ty << 2];
      const float4 b = *(const float4*)&Bs[kk][tx << 2];
      const float ar[4] = {a.x, a.y, a.z, a.w};
      const float br[4] = {b.x, b.y, b.z, b.w};
#pragma unroll
      for (int r = 0; r < 4; r++)
#pragma unroll
        for (int c = 0; c < 4; c++)
          acc[r][c] = fmaf(ar[r], br[c], acc[r][c]);
#pragma unroll
      for (int r = 0; r < 4; r++) qa[r] = fmaf(ar[r], ar[r], qa[r]);
#pragma unroll
      for (int c = 0; c < 4; c++) cs[c] = fmaf(br[c], br[c], cs[c]);
    }
    __syncthreads();
  }
#pragma unroll
  for (int r = 0; r < 4; r++) {
    const int row = rb + (ty << 2) + r;
    const int col = cb0 + (tx << 2);
    float4 v;
    v.x = qa[r] + cs[0] - 2.0f * acc[r][0];
    v.y = qa[r] + cs[1] - 2.0f * acc[r][1];
    v.z = qa[r] + cs[2] - 2.0f * acc[r][2];
    v.w = qa[r] + cs[3] - 2.0f * acc[r][3];
    *(float4*)&lut[row * 2048 + m * 256 + col] = v;
  }
}

// ---------------- Kernel 3a: 8-ROW b64 fused scan+select --------------------
// R8 post-mortem: stride-9 "random bank" layout DOUBLED conflicts (11.5M vs
// 4.7M) -- randomizing 64 lanes over 32 banks gives E[max]~6 vs the
// deterministic 16-replica layout's ~4. Revert to deterministic banking and
// halve the ACCESS COUNT instead: i8 table holds 4 rows/dword, so an
// aligned b64 serves 8 rows. Blocks own 8 rows; grid = 128 rowgroups x 2
// item-halves = 256 (1/CU). Entry e -> 8 replica qwords (stride 64B); lane
// r=tid&7 reads dwords {16(e&1)+2r,+1}: per-r-group Binomial(8,1/2) over 2
// pair-slots, extra ~2 cyc/access, half R7's conflict total. SWAR 4 accs
// (rows 0-3 lo dword, 4-7 hi; max 2040/u16). Partials+combine as R8.
// LDS: 128KB table + 16KB temps = 144KB.
extern __shared__ char dyn_lds[];

__launch_bounds__(1024)
__global__ void scansel_kernel(const float* __restrict__ lutf,
                               const uint4* __restrict__ poffs,
                               const unsigned long long* __restrict__ pcodes,
                               const int* __restrict__ value_codes,
                               const float* __restrict__ vcb,
                               float* __restrict__ partials,
                               float2* __restrict__ mW) {
  char* repb = dyn_lds;                                       // 131072 B table
  unsigned char* temps = (unsigned char*)(dyn_lds + 131072);  // 16 KB
  unsigned long long* tempq = (unsigned long long*)(dyn_lds + 131072);
  const int tid = threadIdx.x;
  const int g = blockIdx.x >> 1;          // rowgroup 0..127 (rows 8g..8g+7)
  const int hf = blockIdx.x & 1;          // item half

  // ---- quantize: 64 tasks (row rr = t&7, seg = t>>3); wave w: t = w+16*t0
  {
    const int w = tid >> 6, lane = tid & 63;
#pragma unroll
    for (int t0 = 0; t0 < 4; t0++) {
      const int t = w + t0 * 16;
      const int rr = t & 7, seg = t >> 3;
      const int row = (g << 3) + rr;
      const int e0 = seg * 256 + lane * 4;
      const float4 v4 = *(const float4*)&lutf[row * 2048 + e0];
      float s4 = v4.x + v4.y + v4.z + v4.w;
#pragma unroll
      for (int off = 32; off > 0; off >>= 1) s4 += __shfl_xor(s4, off);
      const float mean = s4 * (1.0f / 256.0f);
      const float vals[4] = {v4.x, v4.y, v4.z, v4.w};
#pragma unroll
      for (int k = 0; k < 4; k++) {
        int iv = (int)rintf(vals[k] - mean);
        iv = max(-127, min(127, iv));
        temps[(e0 + k) * 8 + rr] = (unsigned char)(iv + 128);
      }
    }
  }
  __syncthreads();

  // ---- replicate: entry e -> 8 replica qwords at qword e*8+r (b128 pairs)
  {
    const int lane = tid & 63;
    const unsigned long long q0 = tempq[tid * 2];
    const unsigned long long q1 = tempq[tid * 2 + 1];
    const uint4 w0 = make_uint4((unsigned)q0, (unsigned)(q0 >> 32),
                                (unsigned)q0, (unsigned)(q0 >> 32));
    const uint4 w1 = make_uint4((unsigned)q1, (unsigned)(q1 >> 32),
                                (unsigned)q1, (unsigned)(q1 >> 32));
    uint4* repv = (uint4*)dyn_lds;
#pragma unroll
    for (int k = 0; k < 4; k++) {
      const int kk = (k + lane) & 3;
      repv[tid * 8 + kk] = w0;
      repv[tid * 8 + 4 + kk] = w1;
    }
  }
  __syncthreads();

  // ---- scan: 32 items/lane, ping-pong-buffered 8 qword lookups/item ----
  const int r = tid & 7;
  const char* base0 = repb + (r << 3);            // segments 0..3 via imm offs
  const char* base1 = repb + 65536 + (r << 3);    // segments 4..7
  unsigned k0[8], k1[8];
#pragma unroll
  for (int j = 0; j < 8; j++) { k0[j] = 0xFFFFFFFFu; k1[j] = 0xFFFFFFFFu; }

  uint2 A[8], B[8];

  auto issue = [&](uint2 (&BUF)[8], const uint4 cw) {
    BUF[0] = *(const uint2*)(base0 + (cw.x & 0xFFFFu));
    BUF[1] = *(const uint2*)(base0 + (cw.x >> 16) + 16384);
    BUF[2] = *(const uint2*)(base0 + (cw.y & 0xFFFFu) + 32768);
    BUF[3] = *(const uint2*)(base0 + (cw.y >> 16) + 49152);
    BUF[4] = *(const uint2*)(base1 + (cw.z & 0xFFFFu));
    BUF[5] = *(const uint2*)(base1 + (cw.z >> 16) + 16384);
    BUF[6] = *(const uint2*)(base1 + (cw.w & 0xFFFFu) + 32768);
    BUF[7] = *(const uint2*)(base1 + (cw.w >> 16) + 49152);
  };

  auto consume = [&](const uint2 (&BUF)[8], const int it) {
    const unsigned M = 0x00FF00FFu;
    unsigned aA = BUF[0].x & M, aB = (BUF[0].x >> 8) & M;
    unsigned aC = BUF[0].y & M, aD = (BUF[0].y >> 8) & M;
#pragma unroll
    for (int j = 1; j < 8; j++) {
      aA += BUF[j].x & M; aB += (BUF[j].x >> 8) & M;
      aC += BUF[j].y & M; aD += (BUF[j].y >> 8) & M;
    }
    const int ss[8] = {(int)(aA & 0xFFFFu), (int)(aB & 0xFFFFu),
                       (int)(aA >> 16),     (int)(aB >> 16),
                       (int)(aC & 0xFFFFu), (int)(aD & 0xFFFFu),
                       (int)(aC >> 16),     (int)(aD >> 16)};
#pragma unroll
    for (int j = 0; j < 8; j++) {
      const unsigned key = ((unsigned)ss[j] << 6) | (unsigned)it;
      const unsigned mx = (k0[j] > key) ? k0[j] : key;
      k0[j] = (k0[j] < key) ? k0[j] : key;
      k1[j] = (k1[j] < mx) ? k1[j] : mx;
    }
  };

  const int nb = (hf << 15) + tid;        // poffs index base for this half
  {
    const uint4 cA = poffs[nb];
    issue(A, cA);
  }
  uint4 cNxt = poffs[nb + 1024];

  for (int it = 0; it < 32; it += 2) {
    const uint4 c2 = poffs[nb + (((it + 2) & 31) << 10)];
    const uint4 c3 = poffs[nb + (((it + 3) & 31) << 10)];
    issue(B, cNxt);
    consume(A, it);
    issue(A, c2);
    consume(B, it + 1);
    cNxt = c3;
  }

  // ================= SELECT PHASE (table dead; overlay LDS) ================
  __syncthreads();

  unsigned* cl  = (unsigned*)dyn_lds;                       // [8][256] 8KB
  float* wts    = (float*)(dyn_lds + 8192);                 // [8][256] 8KB
  unsigned long long* sv8 = (unsigned long long*)(dyn_lds + 16384); // 16KB
  float* gred   = (float*)(dyn_lds + 32768);                // [8][2]
  unsigned* rmin = (unsigned*)(dyn_lds + 32832);            // [8]
  int* rcnt     = (int*)(dyn_lds + 32864);                  // [8]
  float* dmin8  = (float*)(dyn_lds + 32896);                // [8]
  float* wsum8  = (float*)(dyn_lds + 32928);                // [8]

  if (tid < 8) { rmin[tid] = 0xFFFFFFFFu; rcnt[tid] = 0; }
  __syncthreads();

#pragma unroll
  for (int j = 0; j < 8; j++) {
    unsigned d = k0[j] >> 6;
#pragma unroll
    for (int off = 32; off > 0; off >>= 1) {
      const unsigned o = __shfl_xor(d, off);
      d = (o < d) ? o : d;
    }
    if ((tid & 63) == 0) atomicMin(&rmin[j], d);
  }
  __syncthreads();

  {
    const int lane = tid & 63;
    const unsigned long long lm = (1ull << lane) - 1ull;
#pragma unroll
    for (int j = 0; j < 8; j++) {
      const unsigned lim = rmin[j] + 20u;
#pragma unroll
      for (int c = 0; c < 2; c++) {
        const unsigned key = c ? k1[j] : k0[j];
        const unsigned d = key >> 6;
        const bool pred = d <= lim;
        const unsigned long long m = __ballot(pred);
        int base = 0;
        if (lane == 0 && m) base = atomicAdd(&rcnt[j], __popcll(m));
        base = __shfl(base, 0);
        if (pred) {
          const int pos = base + __popcll(m & lm);
          if (pos < 256)
            cl[j * 256 + pos] = (d << 16) | ((key & 63u) << 10) | (unsigned)tid;
        }
      }
    }
  }
  __syncthreads();

  // exact fp32 re-score: group gj = tid>>7 (128 threads) handles row gj,
  // 2 candidate slots per thread.
  const int gj = tid >> 7, gt = tid & 127;
  const int cnt_g = min(rcnt[gj], 256);
  float dex[2] = {1e30f, 1e30f};
#pragma unroll
  for (int s2 = 0; s2 < 2; s2++) {
    const int ci = gt + (s2 << 7);
    if (ci < cnt_g) {
      const unsigned pc = cl[gj * 256 + ci];
      const int n = (hf << 15) + (int)(pc & 0x7FFFu);
      const unsigned long long c8 = pcodes[n];
      const uint4 vc0 = *(const uint4*)&value_codes[n * 8];
      const uint4 vc1 = *(const uint4*)&value_codes[n * 8 + 4];
      sv8[gj * 256 + ci] =
          (unsigned long long)(vc0.x & 255u)        | ((unsigned long long)(vc0.y & 255u) << 8)  |
          ((unsigned long long)(vc0.z & 255u) << 16) | ((unsigned long long)(vc0.w & 255u) << 24) |
          ((unsigned long long)(vc1.x & 255u) << 32) | ((unsigned long long)(vc1.y & 255u) << 40) |
          ((unsigned long long)(vc1.z & 255u) << 48) | ((unsigned long long)(vc1.w & 255u) << 56);
      const float* lrow = lutf + ((g << 3) + gj) * 2048;
      const unsigned lo = (unsigned)c8, hi = (unsigned)(c8 >> 32);
      float dx;
      dx  = lrow[        (lo       & 255u)];
      dx += lrow[ 256 + ((lo >>  8) & 255u)];
      dx += lrow[ 512 + ((lo >> 16) & 255u)];
      dx += lrow[ 768 + ((lo >> 24)       )];
      dx += lrow[1024 + ( hi        & 255u)];
      dx += lrow[1280 + ((hi >>  8) & 255u)];
      dx += lrow[1536 + ((hi >> 16) & 255u)];
      dx += lrow[1792 + ((hi >> 24)       )];
      dex[s2] = dx;
    }
  }
  float mnf = fminf(dex[0], dex[1]);
#pragma unroll
  for (int off = 32; off > 0; off >>= 1) mnf = fminf(mnf, __shfl_xor(mnf, off));
  if ((tid & 63) == 0) gred[gj * 2 + ((tid >> 6) & 1)] = mnf;
  __syncthreads();
  const float dminx = fminf(gred[gj * 2], gred[gj * 2 + 1]);
  float wloc = 0.f;
#pragma unroll
  for (int s2 = 0; s2 < 2; s2++) {
    const int ci = gt + (s2 << 7);
    const float wv = (ci < cnt_g) ? __expf(dminx - dex[s2]) : 0.f;
    wts[gj * 256 + ci] = wv;
    wloc += wv;
  }
#pragma unroll
  for (int off = 32; off > 0; off >>= 1) wloc += __shfl_xor(wloc, off);
  __syncthreads();   // all dminx reads done; safe to overwrite gred
  if ((tid & 63) == 0) gred[gj * 2 + ((tid >> 6) & 1)] = wloc;
  __syncthreads();
  if (gt == 0) {
    dmin8[gj] = dminx;
    wsum8[gj] = gred[gj * 2] + gred[gj * 2 + 1];
  }
  __syncthreads();

  if (tid < 8)
    mW[((g << 3) + tid) * 2 + hf] = make_float2(dmin8[tid], wsum8[tid]);

  // partial value gather: 4 passes x 2 rows (hp = tid>>9 picks row of pair)
  const int hp = tid >> 9, u = tid & 511;
  const int col = u << 2;
  const int mv = col >> 8;
  const int co = col & 255;
  const float* vb2 = vcb + mv * 65536 + co;
#pragma unroll
  for (int jr = 0; jr < 4; jr++) {
    const int j = (jr << 1) | hp;
    const int row = (g << 3) + j;
    const int cj = min(rcnt[j], 256);
    float4 acc = make_float4(0.f, 0.f, 0.f, 0.f);
    int k = 0;
    for (; k + 1 < cj; k += 2) {
      const float w0 = wts[j * 256 + k];
      const float w1 = wts[j * 256 + k + 1];
      const unsigned c0 = (unsigned)((sv8[j * 256 + k] >> (mv * 8)) & 255ull);
      const unsigned c1 = (unsigned)((sv8[j * 256 + k + 1] >> (mv * 8)) & 255ull);
      const float4 v0 = *(const float4*)(vb2 + c0 * 256);
      const float4 v1 = *(const float4*)(vb2 + c1 * 256);
      acc.x = fmaf(w0, v0.x, acc.x); acc.y = fmaf(w0, v0.y, acc.y);
      acc.z = fmaf(w0, v0.z, acc.z); acc.w = fmaf(w0, v0.w, acc.w);
      acc.x = fmaf(w1, v1.x, acc.x); acc.y = fmaf(w1, v1.y, acc.y);
      acc.z = fmaf(w1, v1.z, acc.z); acc.w = fmaf(w1, v1.w, acc.w);
    }
    if (k < cj) {
      const float w0 = wts[j * 256 + k];
      const unsigned c0 = (unsigned)((sv8[j * 256 + k] >> (mv * 8)) & 255ull);
      const float4 v0 = *(const float4*)(vb2 + c0 * 256);
      acc.x = fmaf(w0, v0.x, acc.x); acc.y = fmaf(w0, v0.y, acc.y);
      acc.z = fmaf(w0, v0.z, acc.z); acc.w = fmaf(w0, v0.w, acc.w);
    }
    *(float4*)&partials[((row << 1) + hf) * 2048 + col] = acc;
  }
}

// ---------------- Kernel 3c: exact softmax combine of the two halves --------
__launch_bounds__(256)
__global__ void combine_kernel(const float* __restrict__ partials,
                               const float2* __restrict__ mW,
                               const float* __restrict__ bias,
                               float* __restrict__ out) {
  const int row = blockIdx.x;
  const int t = threadIdx.x;
  const float2 mw0 = mW[row * 2];
  const float2 mw1 = mW[row * 2 + 1];
  const float m = fminf(mw0.x, mw1.x);
  const float a0 = __expf(m - mw0.x);
  const float a1 = __expf(m - mw1.x);
  const float inv = 1.0f / fmaf(a0, mw0.y, a1 * mw1.y);
  const int c = t * 8;
  const float* p0 = partials + (row * 2) * 2048 + c;
  const float* p1 = partials + (row * 2 + 1) * 2048 + c;
#pragma unroll
  for (int v = 0; v < 2; v++) {
    const float4 x0 = *(const float4*)(p0 + v * 4);
    const float4 x1 = *(const float4*)(p1 + v * 4);
    const float4 bb = *(const float4*)&bias[c + v * 4];
    float4 o;
    o.x = fmaf(fmaf(a0, x0.x, a1 * x1.x), inv, bb.x);
    o.y = fmaf(fmaf(a0, x0.y, a1 * x1.y), inv, bb.y);
    o.z = fmaf(fmaf(a0, x0.z, a1 * x1.z), inv, bb.z);
    o.w = fmaf(fmaf(a0, x0.w, a1 * x1.w), inv, bb.w);
    *(float4*)&out[row * 2048 + c + v * 4] = o;
  }
}

// ---------------- Kernel 3b: fallback 64KB scan (verified) ----------------
__launch_bounds__(512)
__global__ void scan16_kernel(const float* __restrict__ lut,
                              const unsigned long long* __restrict__ pcodes,
                              unsigned* __restrict__ cand_d,
                              unsigned short* __restrict__ cand_n) {
  __shared__ short sRep[32768];
  const int tid = threadIdx.x;
  const int b = blockIdx.x;

  const float4 v4 = *(const float4*)&lut[b * 2048 + tid * 4];
  float s4 = v4.x + v4.y + v4.z + v4.w;
#pragma unroll
  for (int off = 32; off > 0; off >>= 1) s4 += __shfl_xor(s4, off);
  const float mean = s4 * (1.0f / 256.0f);

  const float vals[4] = {v4.x, v4.y, v4.z, v4.w};
#pragma unroll
  for (int k2 = 0; k2 < 4; k2++) {
    float f = (vals[k2] - mean) * 64.0f;
    f = fmaxf(fminf(f, 32000.0f), -32000.0f);
    const int iv = (int)rintf(f);
    const unsigned hw = (unsigned)(unsigned short)iv;
    const unsigned wrd = hw | (hw << 16);
    const uint4 wv = make_uint4(wrd, wrd, wrd, wrd);
    const int e = tid * 4 + k2;
    *(uint4*)&((unsigned*)sRep)[e * 8] = wv;
    *(uint4*)&((unsigned*)sRep)[e * 8 + 4] = wv;
  }
  __syncthreads();

  const int r = tid & 15;
  int d0 = 0x7FFFFFFF, d1 = 0x7FFFFFFF, d2 = 0x7FFFFFFF, d3 = 0x7FFFFFFF;
  int i0 = 0, i1 = 0, i2 = 0, i3 = 0;

  unsigned long long c8 = pcodes[tid];
  for (int it = 0; it < 128; it++) {
    const int n = tid + (it << 9);
    unsigned long long nxt = 0ull;
    if (it < 127) nxt = pcodes[n + 512];
    const unsigned lo = (unsigned)c8;
    const unsigned hi = (unsigned)(c8 >> 32);
    int s;
    s  = sRep[(((lo      ) & 255u) << 4) + r        ];
    s += sRep[(((lo >>  8) & 255u) << 4) + r +  4096];
    s += sRep[(((lo >> 16) & 255u) << 4) + r +  8192];
    s += sRep[(((lo >> 24)       ) << 4) + r + 12288];
    s += sRep[(((hi      ) & 255u) << 4) + r + 16384];
    s += sRep[(((hi >>  8) & 255u) << 4) + r + 20480];
    s += sRep[(((hi >> 16) & 255u) << 4) + r + 24576];
    s += sRep[(((hi >> 24)       ) << 4) + r + 28672];
    if (s < d3) {
      if (s < d1) {
        if (s < d0) { d3 = d2; i3 = i2; d2 = d1; i2 = i1; d1 = d0; i1 = i0; d0 = s; i0 = n; }
        else        { d3 = d2; i3 = i2; d2 = d1; i2 = i1; d1 = s; i1 = n; }
      } else {
        if (s < d2) { d3 = d2; i3 = i2; d2 = s; i2 = n; }
        else        { d3 = s; i3 = n; }
      }
    }
    c8 = nxt;
  }

  const int base = b * 2048 + tid * 4;
  const uint4 dv = make_uint4((unsigned)(d0 + 0x40000000), (unsigned)(d1 + 0x40000000),
                              (unsigned)(d2 + 0x40000000), (unsigned)(d3 + 0x40000000));
  *(uint4*)&cand_d[base] = dv;
  const unsigned ni01 = (unsigned)i0 | ((unsigned)i1 << 16);
  const unsigned ni23 = (unsigned)i2 | ((unsigned)i3 << 16);
  *(uint2*)&cand_n[base] = make_uint2(ni01, ni23);
}

// ---------------- Kernel 4 (fallback path only): select + re-score ----------
__launch_bounds__(256)
__global__ void select_kernel(const unsigned* __restrict__ cand_d,
                              const unsigned short* __restrict__ cand_n,
                              const int* __restrict__ value_codes,
                              const float* __restrict__ vcb,
                              const float* __restrict__ bias,
                              const unsigned long long* __restrict__ pcodes,
                              const float* __restrict__ lutf,
                              const unsigned lim_add,
                              float* __restrict__ out) {
  __shared__ unsigned sredw[4];
  __shared__ float sredf[4];
  __shared__ unsigned long long clist[256];
  __shared__ float sw[256];
  __shared__ int svc[2048];
  __shared__ int scnt;
  __shared__ float sWsum;

  const int tid = threadIdx.x;
  const int b = blockIdx.x;

  const uint4 a0 = *(const uint4*)&cand_d[b * 2048 + tid * 8];
  const uint4 a1 = *(const uint4*)&cand_d[b * 2048 + tid * 8 + 4];
  const uint4 nn = *(const uint4*)&cand_n[b * 2048 + tid * 8];
  unsigned dk[8] = {a0.x, a0.y, a0.z, a0.w, a1.x, a1.y, a1.z, a1.w};
  unsigned ni[8] = {nn.x & 0xFFFFu, nn.x >> 16, nn.y & 0xFFFFu, nn.y >> 16,
                    nn.z & 0xFFFFu, nn.z >> 16, nn.w & 0xFFFFu, nn.w >> 16};

  if (tid == 0) scnt = 0;
  unsigned mn = dk[0];
#pragma unroll
  for (int j = 1; j < 8; j++) mn = (dk[j] < mn) ? dk[j] : mn;
#pragma unroll
  for (int off = 32; off > 0; off >>= 1) {
    const unsigned o = __shfl_xor(mn, off);
    mn = (o < mn) ? o : mn;
  }
  if ((tid & 63) == 0) sredw[tid >> 6] = mn;
  __syncthreads();
  unsigned sMin = sredw[0];
  sMin = (sredw[1] < sMin) ? sredw[1] : sMin;
  sMin = (sredw[2] < sMin) ? sredw[2] : sMin;
  sMin = (sredw[3] < sMin) ? sredw[3] : sMin;
  const unsigned lim = sMin + lim_add;

  const int lane = tid & 63;
  const unsigned long long lm = (1ull << lane) - 1ull;
#pragma unroll
  for (int j = 0; j < 8; j++) {
    const bool pred = dk[j] <= lim;
    const unsigned long long mask = __ballot(pred);
    int base = 0;
    if (lane == 0 && mask) base = atomicAdd(&scnt, __popcll(mask));
    base = __shfl(base, 0);
    if (pred) {
      const int pos = base + __popcll(mask & lm);
      if (pos < 256) clist[pos] = ((unsigned long long)dk[j] << 32) | ni[j];
    }
  }
  __syncthreads();
  const int cnt = min(scnt, 256);

  float dex = 1e30f;
  if (tid < cnt) {
    const int n = (int)(clist[tid] & 0xFFFFFFFFu);
    const unsigned long long c8 = pcodes[n];
    const float* lrow = lutf + b * 2048;
    const unsigned lo = (unsigned)c8, hi = (unsigned)(c8 >> 32);
    dex  = lrow[        (lo       & 255u)];
    dex += lrow[ 256 + ((lo >>  8) & 255u)];
    dex += lrow[ 512 + ((lo >> 16) & 255u)];
    dex += lrow[ 768 + ((lo >> 24)       )];
    dex += lrow[1024 + ( hi        & 255u)];
    dex += lrow[1280 + ((hi >>  8) & 255u)];
    dex += lrow[1536 + ((hi >> 16) & 255u)];
    dex += lrow[1792 + ((hi >> 24)       )];
  }
  for (int i = tid; i < (cnt << 3); i += 256)
    svc[i] = value_codes[((int)(clist[i >> 3] & 0xFFFFFFFFu)) * 8 + (i & 7)];
  float mnf = dex;
#pragma unroll
  for (int off = 32; off > 0; off >>= 1) mnf = fminf(mnf, __shfl_xor(mnf, off));
  if ((tid & 63) == 0) sredf[tid >> 6] = mnf;
  __syncthreads();
  const float dminx = fminf(fminf(sredf[0], sredf[1]), fminf(sredf[2], sredf[3]));
  if (tid < cnt) sw[tid] = __expf(dminx - dex);
  __syncthreads();

  if (tid < 64) {
    float s = 0.f;
    for (int j = tid; j < cnt; j += 64) s += sw[j];
#pragma unroll
    for (int off = 32; off > 0; off >>= 1) s += __shfl_xor(s, off);
    if (tid == 0) sWsum = s;
  }
  __syncthreads();
  const float inv = 1.0f / sWsum;

  const int c0 = tid << 3;
  const int mv = c0 >> 8;
  const int off = c0 & 255;
  float4 acc0 = make_float4(0.f, 0.f, 0.f, 0.f);
  float4 acc1 = make_float4(0.f, 0.f, 0.f, 0.f);
  const float* vbase = vcb + mv * 65536 + off;
  for (int k = 0; k < cnt; k++) {
    const float w = sw[k];
    const float* vp = vbase + svc[(k << 3) + mv] * 256;
    const float4 v0 = *(const float4*)vp;
    const float4 v1 = *(const float4*)(vp + 4);
    acc0.x = fmaf(w, v0.x, acc0.x); acc0.y = fmaf(w, v0.y, acc0.y);
    acc0.z = fmaf(w, v0.z, acc0.z); acc0.w = fmaf(w, v0.w, acc0.w);
    acc1.x = fmaf(w, v1.x, acc1.x); acc1.y = fmaf(w, v1.y, acc1.y);
    acc1.z = fmaf(w, v1.z, acc1.z); acc1.w = fmaf(w, v1.w, acc1.w);
  }
  const float4 b0 = *(const float4*)&bias[c0];
  const float4 b1 = *(const float4*)&bias[c0 + 4];
  *(float4*)&out[b * 2048 + c0] =
      make_float4(fmaf(acc0.x, inv, b0.x), fmaf(acc0.y, inv, b0.y),
                  fmaf(acc0.z, inv, b0.z), fmaf(acc0.w, inv, b0.w));
  *(float4*)&out[b * 2048 + c0 + 4] =
      make_float4(fmaf(acc1.x, inv, b1.x), fmaf(acc1.y, inv, b1.y),
                  fmaf(acc1.z, inv, b1.z), fmaf(acc1.w, inv, b1.w));
}

// ---------------- launch ----------------
extern "C" void kernel_launch(void* const* d_in, const int* in_sizes, int n_in,
                              void* d_out, int out_size, void* d_ws, size_t ws_size,
                              hipStream_t stream) {
  const float* x    = (const float*)d_in[0];
  const float* W    = (const float*)d_in[1];
  const float* kcb  = (const float*)d_in[2];
  const float* vcb  = (const float*)d_in[3];
  const float* bias = (const float*)d_in[4];
  const int* key_codes   = (const int*)d_in[5];
  const int* value_codes = (const int*)d_in[6];
  float* out = (float*)d_out;

  // ws: qpart 32MB | q 4MB | lut 8MB | poffs 1MB | pcodes 0.5MB |
  //     partials 16MB | mW 16KB.  cand buffers (fallback only) alias qpart.
  float* qpart = (float*)d_ws;
  float* q     = qpart + 8388608;
  float* lut   = q + 1048576;
  uint4* poffs = (uint4*)(lut + 2097152);
  unsigned long long* pcodes = (unsigned long long*)(poffs + 65536);
  float* partials = (float*)(pcodes + 65536);
  float2* mW = (float2*)(partials + 4194304);
  unsigned* cand_d = (unsigned*)d_ws;
  unsigned short* cand_n = (unsigned short*)(cand_d + 2097152);

  hipLaunchKernelGGL(gemm_q_kernel, dim3(8, 8, 8), dim3(256), 0, stream,
                     x, W, qpart);
  hipLaunchKernelGGL(qsum_kernel, dim3(512), dim3(256), 0, stream,
                     (const float4*)qpart, (float4*)q);
  hipLaunchKernelGGL(lut_kernel, dim3(4, 16, 9), dim3(256), 0, stream,
                     q, kcb, key_codes, lut, pcodes, poffs);

  const hipError_t attr_rc = hipFuncSetAttribute(
      (const void*)scansel_kernel, hipFuncAttributeMaxDynamicSharedMemorySize, 147456);
  if (attr_rc == hipSuccess) {
    hipLaunchKernelGGL(scansel_kernel, dim3(256), dim3(1024), 147456, stream,
                       lut, poffs, pcodes, value_codes, vcb, partials, mW);
    hipLaunchKernelGGL(combine_kernel, dim3(1024), dim3(256), 0, stream,
                       partials, mW, bias, out);
  } else {
    hipLaunchKernelGGL(scan16_kernel, dim3(1024), dim3(512), 0, stream,
                       lut, pcodes, cand_d, cand_n);
    hipLaunchKernelGGL(select_kernel, dim3(1024), dim3(256), 0, stream,
                       cand_d, cand_n, value_codes, vcb, bias, pcodes, lut,
                       1024u, out);
  }
}

// Round 10
// 165.824 us; speedup vs baseline: 1.0718x; 1.0718x over previous
//
#include <hip/hip_runtime.h>

#define N_ITEMS 65536

// ---------------- Kernel 1: qpart[z] = x @ W (K-chunk 128 per z) ------------
__launch_bounds__(256)
__global__ void gemm_q_kernel(const float* __restrict__ A,
                              const float* __restrict__ W,
                              float* __restrict__ qpart) {
  __shared__ float As[16][132];
  __shared__ float Bs[16][132];
  const int tid = threadIdx.x;
  const int tx = tid & 15, ty = tid >> 4;
  const int rb = blockIdx.y * 128, cb = blockIdx.x * 128;
  const int kz = blockIdx.z * 128;
  const int ar = tid >> 2, ac = (tid & 3) << 2;
  const int bk = tid >> 5, bc = (tid & 31) << 2;

  float4 va0 = *(const float4*)&A[(rb + ar) * 1024 + kz + ac];
  float4 va1 = *(const float4*)&A[(rb + ar + 64) * 1024 + kz + ac];
  float4 vb0 = *(const float4*)&W[(kz + bk) * 1024 + cb + bc];
  float4 vb1 = *(const float4*)&W[(kz + bk + 8) * 1024 + cb + bc];

  float acc[8][8] = {};
  for (int k0 = 0; k0 < 128; k0 += 16) {
    As[ac + 0][ar] = va0.x; As[ac + 1][ar] = va0.y;
    As[ac + 2][ar] = va0.z; As[ac + 3][ar] = va0.w;
    As[ac + 0][ar + 64] = va1.x; As[ac + 1][ar + 64] = va1.y;
    As[ac + 2][ar + 64] = va1.z; As[ac + 3][ar + 64] = va1.w;
    *(float4*)&Bs[bk][bc] = vb0;
    *(float4*)&Bs[bk + 8][bc] = vb1;
    __syncthreads();
    if (k0 + 16 < 128) {
      va0 = *(const float4*)&A[(rb + ar) * 1024 + kz + k0 + 16 + ac];
      va1 = *(const float4*)&A[(rb + ar + 64) * 1024 + kz + k0 + 16 + ac];
      vb0 = *(const float4*)&W[(kz + k0 + 16 + bk) * 1024 + cb + bc];
      vb1 = *(const float4*)&W[(kz + k0 + 16 + bk + 8) * 1024 + cb + bc];
    }
#pragma unroll
    for (int kk = 0; kk < 16; kk++) {
      const float4 a0 = *(const float4*)&As[kk][ty << 2];
      const float4 a1 = *(const float4*)&As[kk][64 + (ty << 2)];
      const float4 b0 = *(const float4*)&Bs[kk][tx << 2];
      const float4 b1 = *(const float4*)&Bs[kk][64 + (tx << 2)];
      const float ar8[8] = {a0.x, a0.y, a0.z, a0.w, a1.x, a1.y, a1.z, a1.w};
      const float br8[8] = {b0.x, b0.y, b0.z, b0.w, b1.x, b1.y, b1.z, b1.w};
#pragma unroll
      for (int r = 0; r < 8; r++)
#pragma unroll
        for (int c = 0; c < 8; c++)
          acc[r][c] = fmaf(ar8[r], br8[c], acc[r][c]);
    }
    __syncthreads();
  }
  float* outp = qpart + blockIdx.z * 1048576;
#pragma unroll
  for (int rh = 0; rh < 2; rh++)
#pragma unroll
    for (int r = 0; r < 4; r++) {
      const int row = rb + rh * 64 + (ty << 2) + r;
      const int ri = rh * 4 + r;
      *(float4*)&outp[row * 1024 + cb + (tx << 2)] =
          make_float4(acc[ri][0], acc[ri][1], acc[ri][2], acc[ri][3]);
      *(float4*)&outp[row * 1024 + cb + 64 + (tx << 2)] =
          make_float4(acc[ri][4], acc[ri][5], acc[ri][6], acc[ri][7]);
    }
}

// ---------------- Kernel 1b: q = sum_z qpart[z] (pure BW) -------------------
__launch_bounds__(256)
__global__ void qsum_kernel(const float4* __restrict__ qp,
                            float4* __restrict__ q) {
  const int i = blockIdx.x * 256 + threadIdx.x;   // 0..131071
  float4 s0 = qp[i];
  float4 s1 = qp[i + 131072];
#pragma unroll
  for (int z = 1; z < 8; z++) {
    const float4 a = qp[z * 262144 + i];
    const float4 b = qp[z * 262144 + i + 131072];
    s0.x += a.x; s0.y += a.y; s0.z += a.z; s0.w += a.w;
    s1.x += b.x; s1.y += b.y; s1.z += b.z; s1.w += b.w;
  }
  q[i] = s0;
  q[i + 131072] = s1;
}

// ---------------- Kernel 2: lut + in-register qsq/csq + code packing ----------
// pack plane (i8 4-row table, 16 replicas): h = segment-local byte offset
// = c*64 (entry stride = 16 replica dwords = 64 B; max 16320, fits u16).
__launch_bounds__(256)
__global__ void lut_kernel(const float* __restrict__ q,
                           const float* __restrict__ kcb,
                           const int* __restrict__ key_codes,
                           float* __restrict__ lut,
                           unsigned long long* __restrict__ pcodes,
                           uint4* __restrict__ poffs) {
  if (blockIdx.z == 8) {
    const int g0 = (((int)blockIdx.y * 4 + (int)blockIdx.x) * 256 + (int)threadIdx.x) * 4;
#pragma unroll
    for (int t = 0; t < 4; t++) {
      const int gid = g0 + t;
      unsigned long long p = 0ull;
      unsigned h[8];
#pragma unroll
      for (int j = 0; j < 8; j++) {
        const unsigned c = (unsigned)key_codes[gid * 8 + j] & 255u;
        p |= (unsigned long long)c << (8 * j);
        h[j] = c << 6;
      }
      pcodes[gid] = p;
      poffs[gid] = make_uint4(h[0] | (h[1] << 16), h[2] | (h[3] << 16),
                              h[4] | (h[5] << 16), h[6] | (h[7] << 16));
    }
    return;
  }

  __shared__ float As[32][68];
  __shared__ float Bs[32][68];
  const int tid = threadIdx.x;
  const int tx = tid & 15, ty = tid >> 4;
  const int m = blockIdx.z;
  const int rb = blockIdx.y * 64;
  const int cb0 = blockIdx.x * 64;
  float acc[4][4] = {};
  float qa[4] = {}, cs[4] = {};
  for (int k0 = 0; k0 < 128; k0 += 32) {
#pragma unroll
    for (int l = 0; l < 2; l++) {
      const int e = tid + l * 256;
      const int row = e >> 3, c4 = (e & 7) << 2;
      const float4 va = *(const float4*)&q[(rb + row) * 1024 + m * 128 + k0 + c4];
      As[c4 + 0][row] = va.x; As[c4 + 1][row] = va.y;
      As[c4 + 2][row] = va.z; As[c4 + 3][row] = va.w;
      const float4 vb = *(const float4*)&kcb[(m * 256 + cb0 + row) * 128 + k0 + c4];
      Bs[c4 + 0][row] = vb.x; Bs[c4 + 1][row] = vb.y;
      Bs[c4 + 2][row] = vb.z; Bs[c4 + 3][row] = vb.w;
    }
    __syncthreads();
#pragma unroll
    for (int kk = 0; kk < 32; kk++) {
      const float4 a = *(const float4*)&As[kk][ty << 2];
      const float4 b = *(const float4*)&Bs[kk][tx << 2];
      const float ar[4] = {a.x, a.y, a.z, a.w};
      const float br[4] = {b.x, b.y, b.z, b.w};
#pragma unroll
      for (int r = 0; r < 4; r++)
#pragma unroll
        for (int c = 0; c < 4; c++)
          acc[r][c] = fmaf(ar[r], br[c], acc[r][c]);
#pragma unroll
      for (int r = 0; r < 4; r++) qa[r] = fmaf(ar[r], ar[r], qa[r]);
#pragma unroll
      for (int c = 0; c < 4; c++) cs[c] = fmaf(br[c], br[c], cs[c]);
    }
    __syncthreads();
  }
#pragma unroll
  for (int r = 0; r < 4; r++) {
    const int row = rb + (ty << 2) + r;
    const int col = cb0 + (tx << 2);
    float4 v;
    v.x = qa[r] + cs[0] - 2.0f * acc[r][0];
    v.y = qa[r] + cs[1] - 2.0f * acc[r][1];
    v.z = qa[r] + cs[2] - 2.0f * acc[r][2];
    v.w = qa[r] + cs[3] - 2.0f * acc[r][3];
    *(float4*)&lut[row * 2048 + m * 256 + col] = v;
  }
}

// ---------------- Kernel 3a: FUSED i8 ADC scan + select + gather (R7 cfg) ---
// R8/R9 post-mortems: both structural bets (stride-9 random banks; 8-row
// b64 + half-split) regressed vs this configuration -- conflicts or
// duplicated-phase overhead ate the gains. This is the R7 best-known
// (165.9us) with ONE fix: poffs codes for issue(A,.) were loaded in the
// SAME iteration (~150cyc before use < ~200cyc L2 latency) -> per-iteration
// vmcnt stall. Now cJ1/cJ2 are carried from the previous iteration (>=1
// full iteration ahead); all poffs loads off the critical path.
// Candidate set/weights bit-identical to R7.
extern __shared__ char dyn_lds[];

__launch_bounds__(1024)
__global__ void scansel_kernel(const float* __restrict__ lutf,
                               const uint4* __restrict__ poffs,
                               const unsigned long long* __restrict__ pcodes,
                               const int* __restrict__ value_codes,
                               const float* __restrict__ vcb,
                               const float* __restrict__ bias,
                               float* __restrict__ out) {
  char* repb = dyn_lds;                               // 131072 B table
  unsigned char* temps = (unsigned char*)(dyn_lds + 131072);  // 8 KB
  unsigned* tempw = (unsigned*)(dyn_lds + 131072);
  const int tid = threadIdx.x;
  const int g = blockIdx.x;

  // ---- quantize: 32 tasks (row rr = t&3, seg = t>>2); wave w does t=w, w+16
  {
    const int w = tid >> 6, lane = tid & 63;
#pragma unroll
    for (int t0 = 0; t0 < 2; t0++) {
      const int t = w + t0 * 16;
      const int rr = t & 3, seg = t >> 2;
      const int row = (g << 2) + rr;
      const int e0 = seg * 256 + lane * 4;
      const float4 v4 = *(const float4*)&lutf[row * 2048 + e0];
      float s4 = v4.x + v4.y + v4.z + v4.w;
#pragma unroll
      for (int off = 32; off > 0; off >>= 1) s4 += __shfl_xor(s4, off);
      const float mean = s4 * (1.0f / 256.0f);
      const float vals[4] = {v4.x, v4.y, v4.z, v4.w};
#pragma unroll
      for (int k = 0; k < 4; k++) {
        int iv = (int)rintf(vals[k] - mean);
        iv = max(-127, min(127, iv));
        temps[(e0 + k) * 4 + rr] = (unsigned char)(iv + 128);
      }
    }
  }
  __syncthreads();

  // ---- replicate: entry e -> 16 consecutive dwords (e*16+r)
  {
    const int lane = tid & 63;
    const unsigned v0 = tempw[tid * 2];
    const unsigned v1 = tempw[tid * 2 + 1];
    const uint4 q0 = make_uint4(v0, v0, v0, v0);
    const uint4 q1 = make_uint4(v1, v1, v1, v1);
    uint4* repv = (uint4*)dyn_lds;
#pragma unroll
    for (int k = 0; k < 4; k++) {
      const int kk = (k + lane) & 3;
      repv[tid * 8 + kk] = q0;
      repv[tid * 8 + 4 + kk] = q1;
    }
  }
  __syncthreads();

  // ---- scan: 64 items/lane, ping-pong-buffered 8 dword lookups/item ----
  const int r = tid & 15;
  const char* base0 = repb + (r << 2);            // segments 0..3 via imm offs
  const char* base1 = repb + 65536 + (r << 2);    // segments 4..7
  unsigned k0[4], k1[4];
#pragma unroll
  for (int j = 0; j < 4; j++) { k0[j] = 0xFFFFFFFFu; k1[j] = 0xFFFFFFFFu; }

  unsigned A[8], B[8];

  auto issue = [&](unsigned (&BUF)[8], const uint4 cw) {
    BUF[0] = *(const unsigned*)(base0 + (cw.x & 0xFFFFu));
    BUF[1] = *(const unsigned*)(base0 + (cw.x >> 16) + 16384);
    BUF[2] = *(const unsigned*)(base0 + (cw.y & 0xFFFFu) + 32768);
    BUF[3] = *(const unsigned*)(base0 + (cw.y >> 16) + 49152);
    BUF[4] = *(const unsigned*)(base1 + (cw.z & 0xFFFFu));
    BUF[5] = *(const unsigned*)(base1 + (cw.z >> 16) + 16384);
    BUF[6] = *(const unsigned*)(base1 + (cw.w & 0xFFFFu) + 32768);
    BUF[7] = *(const unsigned*)(base1 + (cw.w >> 16) + 49152);
  };

  auto consume = [&](const unsigned (&BUF)[8], const int it) {
    const unsigned M = 0x00FF00FFu;
    unsigned accA = BUF[0] & M;
    unsigned accB = (BUF[0] >> 8) & M;
#pragma unroll
    for (int j = 1; j < 8; j++) {
      accA += BUF[j] & M;
      accB += (BUF[j] >> 8) & M;
    }
    const int ss[4] = {(int)(accA & 0xFFFFu), (int)(accB & 0xFFFFu),
                       (int)(accA >> 16), (int)(accB >> 16)};
#pragma unroll
    for (int j = 0; j < 4; j++) {
      const unsigned key = ((unsigned)ss[j] << 6) | (unsigned)it;
      const unsigned mx = (k0[j] > key) ? k0[j] : key;
      k0[j] = (k0[j] < key) ? k0[j] : key;
      k1[j] = (k1[j] < mx) ? k1[j] : mx;
    }
  };

  issue(A, poffs[tid]);                 // item 0
  uint4 cJ1 = poffs[tid + 1024];        // codes for item it+1
  uint4 cJ2 = poffs[tid + 2048];        // codes for item it+2

  for (int it = 0; it < 64; it += 2) {
    // load codes for NEXT iteration (items it+3, it+4); wrap-tail dead
    const uint4 cN1 = poffs[tid + (((it + 3) & 63) << 10)];
    const uint4 cN2 = poffs[tid + (((it + 4) & 63) << 10)];
    issue(B, cJ1);           // item it+1 (codes loaded >=1 iteration ago)
    consume(A, it);
    issue(A, cJ2);           // item it+2 (codes loaded last iteration)
    consume(B, it + 1);
    cJ1 = cN1; cJ2 = cN2;
  }

  // ================= SELECT PHASE (table is dead; overlay LDS) =============
  __syncthreads();   // all table reads complete before overlay writes

  unsigned* cl  = (unsigned*)dyn_lds;                       // [4][256] (d<<16)|n
  float* wts    = (float*)(dyn_lds + 4096);                 // [4][256]
  unsigned long long* sv8 = (unsigned long long*)(dyn_lds + 8192); // [4][256]
  float* gred   = (float*)(dyn_lds + 16384);                // [4][4] scratch
  unsigned* rmin = (unsigned*)(dyn_lds + 16448);            // [4]
  int* rcnt     = (int*)(dyn_lds + 16464);                  // [4]
  float* rws    = (float*)(dyn_lds + 16480);                // [4] 1/wsum

  if (tid < 4) { rmin[tid] = 0xFFFFFFFFu; rcnt[tid] = 0; }
  __syncthreads();

  // per-row quantized min
#pragma unroll
  for (int j = 0; j < 4; j++) {
    unsigned d = k0[j] >> 6;
#pragma unroll
    for (int off = 32; off > 0; off >>= 1) {
      const unsigned o = __shfl_xor(d, off);
      d = (o < d) ? o : d;
    }
    if ((tid & 63) == 0) atomicMin(&rmin[j], d);
  }
  __syncthreads();

  // ballot-compact candidates within window
  {
    const int lane = tid & 63;
    const unsigned long long lm = (1ull << lane) - 1ull;
#pragma unroll
    for (int j = 0; j < 4; j++) {
      const unsigned lim = rmin[j] + 20u;
#pragma unroll
      for (int c = 0; c < 2; c++) {
        const unsigned key = c ? k1[j] : k0[j];
        const unsigned d = key >> 6;
        const bool pred = d <= lim;
        const unsigned long long m = __ballot(pred);
        int base = 0;
        if (lane == 0 && m) base = atomicAdd(&rcnt[j], __popcll(m));
        base = __shfl(base, 0);
        if (pred) {
          const int pos = base + __popcll(m & lm);
          if (pos < 256)
            cl[j * 256 + pos] = (d << 16) | ((key & 63u) << 10) | (unsigned)tid;
        }
      }
    }
  }
  __syncthreads();

  // exact fp32 re-score (group j = tid>>8 handles row j)
  const int gj = tid >> 8, gt = tid & 255;
  const int cnt_g = min(rcnt[gj], 256);
  float dex = 1e30f;
  if (gt < cnt_g) {
    const unsigned pc = cl[gj * 256 + gt];
    const int n = (int)(pc & 0xFFFFu);
    const unsigned long long c8 = pcodes[n];
    const uint4 vc0 = *(const uint4*)&value_codes[n * 8];
    const uint4 vc1 = *(const uint4*)&value_codes[n * 8 + 4];
    sv8[gj * 256 + gt] =
        (unsigned long long)(vc0.x & 255u)        | ((unsigned long long)(vc0.y & 255u) << 8)  |
        ((unsigned long long)(vc0.z & 255u) << 16) | ((unsigned long long)(vc0.w & 255u) << 24) |
        ((unsigned long long)(vc1.x & 255u) << 32) | ((unsigned long long)(vc1.y & 255u) << 40) |
        ((unsigned long long)(vc1.z & 255u) << 48) | ((unsigned long long)(vc1.w & 255u) << 56);
    const float* lrow = lutf + ((g << 2) + gj) * 2048;
    const unsigned lo = (unsigned)c8, hi = (unsigned)(c8 >> 32);
    dex  = lrow[        (lo       & 255u)];
    dex += lrow[ 256 + ((lo >>  8) & 255u)];
    dex += lrow[ 512 + ((lo >> 16) & 255u)];
    dex += lrow[ 768 + ((lo >> 24)       )];
    dex += lrow[1024 + ( hi        & 255u)];
    dex += lrow[1280 + ((hi >>  8) & 255u)];
    dex += lrow[1536 + ((hi >> 16) & 255u)];
    dex += lrow[1792 + ((hi >> 24)       )];
  }
  // group min of dex (4 waves per group)
  float mnf = dex;
#pragma unroll
  for (int off = 32; off > 0; off >>= 1) mnf = fminf(mnf, __shfl_xor(mnf, off));
  if ((tid & 63) == 0) gred[gj * 4 + ((tid >> 6) & 3)] = mnf;
  __syncthreads();
  const float dminx = fminf(fminf(gred[gj * 4], gred[gj * 4 + 1]),
                            fminf(gred[gj * 4 + 2], gred[gj * 4 + 3]));
  const float w = (gt < cnt_g) ? __expf(dminx - dex) : 0.f;
  wts[gj * 256 + gt] = w;
  // group sum of w
  float sw_ = w;
#pragma unroll
  for (int off = 32; off > 0; off >>= 1) sw_ += __shfl_xor(sw_, off);
  __syncthreads();   // gred min-reads done; safe to overwrite
  if ((tid & 63) == 0) gred[gj * 4 + ((tid >> 6) & 3)] = sw_;
  __syncthreads();
  if (gt == 0)
    rws[gj] = 1.0f / (gred[gj * 4] + gred[gj * 4 + 1] + gred[gj * 4 + 2] + gred[gj * 4 + 3]);
  __syncthreads();

  // value gather + output: rows in pairs (h = tid>>9 selects row of pair)
  const int h = tid >> 9, u = tid & 511;
  const int col = u << 2;
  const int mv = col >> 8;
  const int co = col & 255;
  const float* vb2 = vcb + mv * 65536 + co;
  const float4 bb = *(const float4*)&bias[col];
#pragma unroll
  for (int jr = 0; jr < 2; jr++) {
    const int j = (jr << 1) | h;
    const int row = (g << 2) + j;
    const int cj = min(rcnt[j], 256);
    float4 acc = make_float4(0.f, 0.f, 0.f, 0.f);
    int k = 0;
    for (; k + 1 < cj; k += 2) {
      const float w0 = wts[j * 256 + k];
      const float w1 = wts[j * 256 + k + 1];
      const unsigned c0 = (unsigned)((sv8[j * 256 + k] >> (mv * 8)) & 255ull);
      const unsigned c1 = (unsigned)((sv8[j * 256 + k + 1] >> (mv * 8)) & 255ull);
      const float4 v0 = *(const float4*)(vb2 + c0 * 256);
      const float4 v1 = *(const float4*)(vb2 + c1 * 256);
      acc.x = fmaf(w0, v0.x, acc.x); acc.y = fmaf(w0, v0.y, acc.y);
      acc.z = fmaf(w0, v0.z, acc.z); acc.w = fmaf(w0, v0.w, acc.w);
      acc.x = fmaf(w1, v1.x, acc.x); acc.y = fmaf(w1, v1.y, acc.y);
      acc.z = fmaf(w1, v1.z, acc.z); acc.w = fmaf(w1, v1.w, acc.w);
    }
    if (k < cj) {
      const float w0 = wts[j * 256 + k];
      const unsigned c0 = (unsigned)((sv8[j * 256 + k] >> (mv * 8)) & 255ull);
      const float4 v0 = *(const float4*)(vb2 + c0 * 256);
      acc.x = fmaf(w0, v0.x, acc.x); acc.y = fmaf(w0, v0.y, acc.y);
      acc.z = fmaf(w0, v0.z, acc.z); acc.w = fmaf(w0, v0.w, acc.w);
    }
    const float iv = rws[j];
    *(float4*)&out[row * 2048 + col] =
        make_float4(fmaf(acc.x, iv, bb.x), fmaf(acc.y, iv, bb.y),
                    fmaf(acc.z, iv, bb.z), fmaf(acc.w, iv, bb.w));
  }
}

// ---------------- Kernel 3b: fallback 64KB scan (verified) ----------------
__launch_bounds__(512)
__global__ void scan16_kernel(const float* __restrict__ lut,
                              const unsigned long long* __restrict__ pcodes,
                              unsigned* __restrict__ cand_d,
                              unsigned short* __restrict__ cand_n) {
  __shared__ short sRep[32768];
  const int tid = threadIdx.x;
  const int b = blockIdx.x;

  const float4 v4 = *(const float4*)&lut[b * 2048 + tid * 4];
  float s4 = v4.x + v4.y + v4.z + v4.w;
#pragma unroll
  for (int off = 32; off > 0; off >>= 1) s4 += __shfl_xor(s4, off);
  const float mean = s4 * (1.0f / 256.0f);

  const float vals[4] = {v4.x, v4.y, v4.z, v4.w};
#pragma unroll
  for (int k2 = 0; k2 < 4; k2++) {
    float f = (vals[k2] - mean) * 64.0f;
    f = fmaxf(fminf(f, 32000.0f), -32000.0f);
    const int iv = (int)rintf(f);
    const unsigned hw = (unsigned)(unsigned short)iv;
    const unsigned wrd = hw | (hw << 16);
    const uint4 wv = make_uint4(wrd, wrd, wrd, wrd);
    const int e = tid * 4 + k2;
    *(uint4*)&((unsigned*)sRep)[e * 8] = wv;
    *(uint4*)&((unsigned*)sRep)[e * 8 + 4] = wv;
  }
  __syncthreads();

  const int r = tid & 15;
  int d0 = 0x7FFFFFFF, d1 = 0x7FFFFFFF, d2 = 0x7FFFFFFF, d3 = 0x7FFFFFFF;
  int i0 = 0, i1 = 0, i2 = 0, i3 = 0;

  unsigned long long c8 = pcodes[tid];
  for (int it = 0; it < 128; it++) {
    const int n = tid + (it << 9);
    unsigned long long nxt = 0ull;
    if (it < 127) nxt = pcodes[n + 512];
    const unsigned lo = (unsigned)c8;
    const unsigned hi = (unsigned)(c8 >> 32);
    int s;
    s  = sRep[(((lo      ) & 255u) << 4) + r        ];
    s += sRep[(((lo >>  8) & 255u) << 4) + r +  4096];
    s += sRep[(((lo >> 16) & 255u) << 4) + r +  8192];
    s += sRep[(((lo >> 24)       ) << 4) + r + 12288];
    s += sRep[(((hi      ) & 255u) << 4) + r + 16384];
    s += sRep[(((hi >>  8) & 255u) << 4) + r + 20480];
    s += sRep[(((hi >> 16) & 255u) << 4) + r + 24576];
    s += sRep[(((hi >> 24)       ) << 4) + r + 28672];
    if (s < d3) {
      if (s < d1) {
        if (s < d0) { d3 = d2; i3 = i2; d2 = d1; i2 = i1; d1 = d0; i1 = i0; d0 = s; i0 = n; }
        else        { d3 = d2; i3 = i2; d2 = d1; i2 = i1; d1 = s; i1 = n; }
      } else {
        if (s < d2) { d3 = d2; i3 = i2; d2 = s; i2 = n; }
        else        { d3 = s; i3 = n; }
      }
    }
    c8 = nxt;
  }

  const int base = b * 2048 + tid * 4;
  const uint4 dv = make_uint4((unsigned)(d0 + 0x40000000), (unsigned)(d1 + 0x40000000),
                              (unsigned)(d2 + 0x40000000), (unsigned)(d3 + 0x40000000));
  *(uint4*)&cand_d[base] = dv;
  const unsigned ni01 = (unsigned)i0 | ((unsigned)i1 << 16);
  const unsigned ni23 = (unsigned)i2 | ((unsigned)i3 << 16);
  *(uint2*)&cand_n[base] = make_uint2(ni01, ni23);
}

// ---------------- Kernel 4 (fallback path only): select + re-score ----------
__launch_bounds__(256)
__global__ void select_kernel(const unsigned* __restrict__ cand_d,
                              const unsigned short* __restrict__ cand_n,
                              const int* __restrict__ value_codes,
                              const float* __restrict__ vcb,
                              const float* __restrict__ bias,
                              const unsigned long long* __restrict__ pcodes,
                              const float* __restrict__ lutf,
                              const unsigned lim_add,
                              float* __restrict__ out) {
  __shared__ unsigned sredw[4];
  __shared__ float sredf[4];
  __shared__ unsigned long long clist[256];
  __shared__ float sw[256];
  __shared__ int svc[2048];
  __shared__ int scnt;
  __shared__ float sWsum;

  const int tid = threadIdx.x;
  const int b = blockIdx.x;

  const uint4 a0 = *(const uint4*)&cand_d[b * 2048 + tid * 8];
  const uint4 a1 = *(const uint4*)&cand_d[b * 2048 + tid * 8 + 4];
  const uint4 nn = *(const uint4*)&cand_n[b * 2048 + tid * 8];
  unsigned dk[8] = {a0.x, a0.y, a0.z, a0.w, a1.x, a1.y, a1.z, a1.w};
  unsigned ni[8] = {nn.x & 0xFFFFu, nn.x >> 16, nn.y & 0xFFFFu, nn.y >> 16,
                    nn.z & 0xFFFFu, nn.z >> 16, nn.w & 0xFFFFu, nn.w >> 16};

  if (tid == 0) scnt = 0;
  unsigned mn = dk[0];
#pragma unroll
  for (int j = 1; j < 8; j++) mn = (dk[j] < mn) ? dk[j] : mn;
#pragma unroll
  for (int off = 32; off > 0; off >>= 1) {
    const unsigned o = __shfl_xor(mn, off);
    mn = (o < mn) ? o : mn;
  }
  if ((tid & 63) == 0) sredw[tid >> 6] = mn;
  __syncthreads();
  unsigned sMin = sredw[0];
  sMin = (sredw[1] < sMin) ? sredw[1] : sMin;
  sMin = (sredw[2] < sMin) ? sredw[2] : sMin;
  sMin = (sredw[3] < sMin) ? sredw[3] : sMin;
  const unsigned lim = sMin + lim_add;

  const int lane = tid & 63;
  const unsigned long long lm = (1ull << lane) - 1ull;
#pragma unroll
  for (int j = 0; j < 8; j++) {
    const bool pred = dk[j] <= lim;
    const unsigned long long mask = __ballot(pred);
    int base = 0;
    if (lane == 0 && mask) base = atomicAdd(&scnt, __popcll(mask));
    base = __shfl(base, 0);
    if (pred) {
      const int pos = base + __popcll(mask & lm);
      if (pos < 256) clist[pos] = ((unsigned long long)dk[j] << 32) | ni[j];
    }
  }
  __syncthreads();
  const int cnt = min(scnt, 256);

  float dex = 1e30f;
  if (tid < cnt) {
    const int n = (int)(clist[tid] & 0xFFFFFFFFu);
    const unsigned long long c8 = pcodes[n];
    const float* lrow = lutf + b * 2048;
    const unsigned lo = (unsigned)c8, hi = (unsigned)(c8 >> 32);
    dex  = lrow[        (lo       & 255u)];
    dex += lrow[ 256 + ((lo >>  8) & 255u)];
    dex += lrow[ 512 + ((lo >> 16) & 255u)];
    dex += lrow[ 768 + ((lo >> 24)       )];
    dex += lrow[1024 + ( hi        & 255u)];
    dex += lrow[1280 + ((hi >>  8) & 255u)];
    dex += lrow[1536 + ((hi >> 16) & 255u)];
    dex += lrow[1792 + ((hi >> 24)       )];
  }
  for (int i = tid; i < (cnt << 3); i += 256)
    svc[i] = value_codes[((int)(clist[i >> 3] & 0xFFFFFFFFu)) * 8 + (i & 7)];
  float mnf = dex;
#pragma unroll
  for (int off = 32; off > 0; off >>= 1) mnf = fminf(mnf, __shfl_xor(mnf, off));
  if ((tid & 63) == 0) sredf[tid >> 6] = mnf;
  __syncthreads();
  const float dminx = fminf(fminf(sredf[0], sredf[1]), fminf(sredf[2], sredf[3]));
  if (tid < cnt) sw[tid] = __expf(dminx - dex);
  __syncthreads();

  if (tid < 64) {
    float s = 0.f;
    for (int j = tid; j < cnt; j += 64) s += sw[j];
#pragma unroll
    for (int off = 32; off > 0; off >>= 1) s += __shfl_xor(s, off);
    if (tid == 0) sWsum = s;
  }
  __syncthreads();
  const float inv = 1.0f / sWsum;

  const int c0 = tid << 3;
  const int mv = c0 >> 8;
  const int off = c0 & 255;
  float4 acc0 = make_float4(0.f, 0.f, 0.f, 0.f);
  float4 acc1 = make_float4(0.f, 0.f, 0.f, 0.f);
  const float* vbase = vcb + mv * 65536 + off;
  for (int k = 0; k < cnt; k++) {
    const float w = sw[k];
    const float* vp = vbase + svc[(k << 3) + mv] * 256;
    const float4 v0 = *(const float4*)vp;
    const float4 v1 = *(const float4*)(vp + 4);
    acc0.x = fmaf(w, v0.x, acc0.x); acc0.y = fmaf(w, v0.y, acc0.y);
    acc0.z = fmaf(w, v0.z, acc0.z); acc0.w = fmaf(w, v0.w, acc0.w);
    acc1.x = fmaf(w, v1.x, acc1.x); acc1.y = fmaf(w, v1.y, acc1.y);
    acc1.z = fmaf(w, v1.z, acc1.z); acc1.w = fmaf(w, v1.w, acc1.w);
  }
  const float4 b0 = *(const float4*)&bias[c0];
  const float4 b1 = *(const float4*)&bias[c0 + 4];
  *(float4*)&out[b * 2048 + c0] =
      make_float4(fmaf(acc0.x, inv, b0.x), fmaf(acc0.y, inv, b0.y),
                  fmaf(acc0.z, inv, b0.z), fmaf(acc0.w, inv, b0.w));
  *(float4*)&out[b * 2048 + c0 + 4] =
      make_float4(fmaf(acc1.x, inv, b1.x), fmaf(acc1.y, inv, b1.y),
                  fmaf(acc1.z, inv, b1.z), fmaf(acc1.w, inv, b1.w));
}

// ---------------- launch ----------------
extern "C" void kernel_launch(void* const* d_in, const int* in_sizes, int n_in,
                              void* d_out, int out_size, void* d_ws, size_t ws_size,
                              hipStream_t stream) {
  const float* x    = (const float*)d_in[0];
  const float* W    = (const float*)d_in[1];
  const float* kcb  = (const float*)d_in[2];
  const float* vcb  = (const float*)d_in[3];
  const float* bias = (const float*)d_in[4];
  const int* key_codes   = (const int*)d_in[5];
  const int* value_codes = (const int*)d_in[6];
  float* out = (float*)d_out;

  // ws: qpart 32MB | q 4MB | lut 8MB | poffs 1MB | pcodes 0.5MB.
  // cand buffers (fallback only) alias qpart. lut live through scansel.
  float* qpart = (float*)d_ws;
  float* q     = qpart + 8388608;
  float* lut   = q + 1048576;
  uint4* poffs = (uint4*)(lut + 2097152);
  unsigned long long* pcodes = (unsigned long long*)(poffs + 65536);
  unsigned* cand_d = (unsigned*)d_ws;
  unsigned short* cand_n = (unsigned short*)(cand_d + 2097152);

  hipLaunchKernelGGL(gemm_q_kernel, dim3(8, 8, 8), dim3(256), 0, stream,
                     x, W, qpart);
  hipLaunchKernelGGL(qsum_kernel, dim3(512), dim3(256), 0, stream,
                     (const float4*)qpart, (float4*)q);
  hipLaunchKernelGGL(lut_kernel, dim3(4, 16, 9), dim3(256), 0, stream,
                     q, kcb, key_codes, lut, pcodes, poffs);

  const hipError_t attr_rc = hipFuncSetAttribute(
      (const void*)scansel_kernel, hipFuncAttributeMaxDynamicSharedMemorySize, 139264);
  if (attr_rc == hipSuccess) {
    hipLaunchKernelGGL(scansel_kernel, dim3(256), dim3(1024), 139264, stream,
                       lut, poffs, pcodes, value_codes, vcb, bias, out);
  } else {
    hipLaunchKernelGGL(scan16_kernel, dim3(1024), dim3(512), 0, stream,
                       lut, pcodes, cand_d, cand_n);
    hipLaunchKernelGGL(select_kernel, dim3(1024), dim3(256), 0, stream,
                       cand_d, cand_n, value_codes, vcb, bias, pcodes, lut,
                       1024u, out);
  }
}

// Round 11
// 163.518 us; speedup vs baseline: 1.0869x; 1.0141x over previous
//
#include <hip/hip_runtime.h>

#define N_ITEMS 65536

// ---------------- Kernel 1: qpart[z] = x @ W (K-chunk 128) + pack plane ------
// z==8 plane (64 blocks) packs key_codes -> pcodes/poffs (overlaps gemm).
__launch_bounds__(256)
__global__ void gemm_q_kernel(const float* __restrict__ A,
                              const float* __restrict__ W,
                              const int* __restrict__ key_codes,
                              float* __restrict__ qpart,
                              unsigned long long* __restrict__ pcodes,
                              uint4* __restrict__ poffs) {
  if (blockIdx.z == 8) {
    const int g0 = (((int)blockIdx.y * 8 + (int)blockIdx.x) * 256 + (int)threadIdx.x) * 4;
#pragma unroll
    for (int t = 0; t < 4; t++) {
      const int gid = g0 + t;
      unsigned long long p = 0ull;
      unsigned h[8];
#pragma unroll
      for (int j = 0; j < 8; j++) {
        const unsigned c = (unsigned)key_codes[gid * 8 + j] & 255u;
        p |= (unsigned long long)c << (8 * j);
        h[j] = c << 6;
      }
      pcodes[gid] = p;
      poffs[gid] = make_uint4(h[0] | (h[1] << 16), h[2] | (h[3] << 16),
                              h[4] | (h[5] << 16), h[6] | (h[7] << 16));
    }
    return;
  }

  __shared__ float As[16][132];
  __shared__ float Bs[16][132];
  const int tid = threadIdx.x;
  const int tx = tid & 15, ty = tid >> 4;
  const int rb = blockIdx.y * 128, cb = blockIdx.x * 128;
  const int kz = blockIdx.z * 128;
  const int ar = tid >> 2, ac = (tid & 3) << 2;
  const int bk = tid >> 5, bc = (tid & 31) << 2;

  float4 va0 = *(const float4*)&A[(rb + ar) * 1024 + kz + ac];
  float4 va1 = *(const float4*)&A[(rb + ar + 64) * 1024 + kz + ac];
  float4 vb0 = *(const float4*)&W[(kz + bk) * 1024 + cb + bc];
  float4 vb1 = *(const float4*)&W[(kz + bk + 8) * 1024 + cb + bc];

  float acc[8][8] = {};
  for (int k0 = 0; k0 < 128; k0 += 16) {
    As[ac + 0][ar] = va0.x; As[ac + 1][ar] = va0.y;
    As[ac + 2][ar] = va0.z; As[ac + 3][ar] = va0.w;
    As[ac + 0][ar + 64] = va1.x; As[ac + 1][ar + 64] = va1.y;
    As[ac + 2][ar + 64] = va1.z; As[ac + 3][ar + 64] = va1.w;
    *(float4*)&Bs[bk][bc] = vb0;
    *(float4*)&Bs[bk + 8][bc] = vb1;
    __syncthreads();
    if (k0 + 16 < 128) {
      va0 = *(const float4*)&A[(rb + ar) * 1024 + kz + k0 + 16 + ac];
      va1 = *(const float4*)&A[(rb + ar + 64) * 1024 + kz + k0 + 16 + ac];
      vb0 = *(const float4*)&W[(kz + k0 + 16 + bk) * 1024 + cb + bc];
      vb1 = *(const float4*)&W[(kz + k0 + 16 + bk + 8) * 1024 + cb + bc];
    }
#pragma unroll
    for (int kk = 0; kk < 16; kk++) {
      const float4 a0 = *(const float4*)&As[kk][ty << 2];
      const float4 a1 = *(const float4*)&As[kk][64 + (ty << 2)];
      const float4 b0 = *(const float4*)&Bs[kk][tx << 2];
      const float4 b1 = *(const float4*)&Bs[kk][64 + (tx << 2)];
      const float ar8[8] = {a0.x, a0.y, a0.z, a0.w, a1.x, a1.y, a1.z, a1.w};
      const float br8[8] = {b0.x, b0.y, b0.z, b0.w, b1.x, b1.y, b1.z, b1.w};
#pragma unroll
      for (int r = 0; r < 8; r++)
#pragma unroll
        for (int c = 0; c < 8; c++)
          acc[r][c] = fmaf(ar8[r], br8[c], acc[r][c]);
    }
    __syncthreads();
  }
  float* outp = qpart + blockIdx.z * 1048576;
#pragma unroll
  for (int rh = 0; rh < 2; rh++)
#pragma unroll
    for (int r = 0; r < 4; r++) {
      const int row = rb + rh * 64 + (ty << 2) + r;
      const int ri = rh * 4 + r;
      *(float4*)&outp[row * 1024 + cb + (tx << 2)] =
          make_float4(acc[ri][0], acc[ri][1], acc[ri][2], acc[ri][3]);
      *(float4*)&outp[row * 1024 + cb + 64 + (tx << 2)] =
          make_float4(acc[ri][4], acc[ri][5], acc[ri][6], acc[ri][7]);
    }
}

// ---------------- Kernel 1b: q = sum_z qpart[z] (pure BW) -------------------
__launch_bounds__(256)
__global__ void qsum_kernel(const float4* __restrict__ qp,
                            float4* __restrict__ q) {
  const int i = blockIdx.x * 256 + threadIdx.x;   // 0..131071
  float4 s0 = qp[i];
  float4 s1 = qp[i + 131072];
#pragma unroll
  for (int z = 1; z < 8; z++) {
    const float4 a = qp[z * 262144 + i];
    const float4 b = qp[z * 262144 + i + 131072];
    s0.x += a.x; s0.y += a.y; s0.z += a.z; s0.w += a.w;
    s1.x += b.x; s1.y += b.y; s1.z += b.z; s1.w += b.w;
  }
  q[i] = s0;
  q[i + 131072] = s1;
}

// ---------------- Kernel 2: lut + DIRECT i8 table emission ------------------
// i8 value = clamp(rint(dt - qa[r] - 96), -127, 127) + 128
//          = clamp(rint(cs - 2*cross - 96), ...) -- per-(row,seg) offset
// qa[r]+96 is row-constant after the 8-segment sum -> per-row ranking
// identical to mean-centering. High clips UNDERestimate (false candidates,
// exact re-score fixes); low clips (P~2e-8) overestimate <=3, inside the
// lim_add=20 error budget. Layout matches scansel temps: dword = entry
// e = m*256+c of rowgroup gq, byte r = row (gq*4+r).
__launch_bounds__(256)
__global__ void lut_kernel(const float* __restrict__ q,
                           const float* __restrict__ kcb,
                           float* __restrict__ lut,
                           unsigned* __restrict__ i8lut) {
  __shared__ float As[32][68];
  __shared__ float Bs[32][68];
  const int tid = threadIdx.x;
  const int tx = tid & 15, ty = tid >> 4;
  const int m = blockIdx.z;
  const int rb = blockIdx.y * 64;
  const int cb0 = blockIdx.x * 64;
  float acc[4][4] = {};
  float qa[4] = {}, cs[4] = {};
  for (int k0 = 0; k0 < 128; k0 += 32) {
#pragma unroll
    for (int l = 0; l < 2; l++) {
      const int e = tid + l * 256;
      const int row = e >> 3, c4 = (e & 7) << 2;
      const float4 va = *(const float4*)&q[(rb + row) * 1024 + m * 128 + k0 + c4];
      As[c4 + 0][row] = va.x; As[c4 + 1][row] = va.y;
      As[c4 + 2][row] = va.z; As[c4 + 3][row] = va.w;
      const float4 vb = *(const float4*)&kcb[(m * 256 + cb0 + row) * 128 + k0 + c4];
      Bs[c4 + 0][row] = vb.x; Bs[c4 + 1][row] = vb.y;
      Bs[c4 + 2][row] = vb.z; Bs[c4 + 3][row] = vb.w;
    }
    __syncthreads();
#pragma unroll
    for (int kk = 0; kk < 32; kk++) {
      const float4 a = *(const float4*)&As[kk][ty << 2];
      const float4 b = *(const float4*)&Bs[kk][tx << 2];
      const float ar[4] = {a.x, a.y, a.z, a.w};
      const float br[4] = {b.x, b.y, b.z, b.w};
#pragma unroll
      for (int r = 0; r < 4; r++)
#pragma unroll
        for (int c = 0; c < 4; c++)
          acc[r][c] = fmaf(ar[r], br[c], acc[r][c]);
#pragma unroll
      for (int r = 0; r < 4; r++) qa[r] = fmaf(ar[r], ar[r], qa[r]);
#pragma unroll
      for (int c = 0; c < 4; c++) cs[c] = fmaf(br[c], br[c], cs[c]);
    }
    __syncthreads();
  }
  unsigned wpk[4] = {0u, 0u, 0u, 0u};
#pragma unroll
  for (int r = 0; r < 4; r++) {
    const int row = rb + (ty << 2) + r;
    const int col = cb0 + (tx << 2);
    float4 v;
    v.x = qa[r] + cs[0] - 2.0f * acc[r][0];
    v.y = qa[r] + cs[1] - 2.0f * acc[r][1];
    v.z = qa[r] + cs[2] - 2.0f * acc[r][2];
    v.w = qa[r] + cs[3] - 2.0f * acc[r][3];
    *(float4*)&lut[row * 2048 + m * 256 + col] = v;
    const float vb4[4] = {v.x, v.y, v.z, v.w};
#pragma unroll
    for (int c = 0; c < 4; c++) {
      int iv = (int)rintf(vb4[c] - qa[r] - 96.0f);
      iv = max(-127, min(127, iv));
      wpk[c] |= (unsigned)(iv + 128) << (8 * r);
    }
  }
  const int gq = (rb >> 2) + ty;
  const int e0 = m * 256 + cb0 + (tx << 2);
  *(uint4*)&i8lut[gq * 2048 + e0] = make_uint4(wpk[0], wpk[1], wpk[2], wpk[3]);
}

// ---------------- Kernel 3a: FUSED scan+select (quantize phase removed) -----
// Table now loaded pre-quantized from i8lut (8B/lane coalesced) -- drops the
// 8MB lut read, shfl-mean, rintf, byte-scatter LDS stores, and temps region.
// Scan loop / select / gather byte-identical to R10 (best-known 47us cfg).
// LDS: exactly 131072 B (table only).
extern __shared__ char dyn_lds[];

__launch_bounds__(1024)
__global__ void scansel_kernel(const float* __restrict__ lutf,
                               const unsigned* __restrict__ i8lut,
                               const uint4* __restrict__ poffs,
                               const unsigned long long* __restrict__ pcodes,
                               const int* __restrict__ value_codes,
                               const float* __restrict__ vcb,
                               const float* __restrict__ bias,
                               float* __restrict__ out) {
  char* repb = dyn_lds;                               // 131072 B table
  const int tid = threadIdx.x;
  const int g = blockIdx.x;

  // ---- replicate: entry e -> 16 consecutive dwords (e*16+r) ----
  {
    const int lane = tid & 63;
    const uint2 tv = *(const uint2*)&i8lut[g * 2048 + tid * 2];
    const uint4 q0 = make_uint4(tv.x, tv.x, tv.x, tv.x);
    const uint4 q1 = make_uint4(tv.y, tv.y, tv.y, tv.y);
    uint4* repv = (uint4*)dyn_lds;
#pragma unroll
    for (int k = 0; k < 4; k++) {
      const int kk = (k + lane) & 3;
      repv[tid * 8 + kk] = q0;
      repv[tid * 8 + 4 + kk] = q1;
    }
  }
  __syncthreads();

  // ---- scan: 64 items/lane, ping-pong-buffered 8 dword lookups/item ----
  const int r = tid & 15;
  const char* base0 = repb + (r << 2);            // segments 0..3 via imm offs
  const char* base1 = repb + 65536 + (r << 2);    // segments 4..7
  unsigned k0[4], k1[4];
#pragma unroll
  for (int j = 0; j < 4; j++) { k0[j] = 0xFFFFFFFFu; k1[j] = 0xFFFFFFFFu; }

  unsigned A[8], B[8];

  auto issue = [&](unsigned (&BUF)[8], const uint4 cw) {
    BUF[0] = *(const unsigned*)(base0 + (cw.x & 0xFFFFu));
    BUF[1] = *(const unsigned*)(base0 + (cw.x >> 16) + 16384);
    BUF[2] = *(const unsigned*)(base0 + (cw.y & 0xFFFFu) + 32768);
    BUF[3] = *(const unsigned*)(base0 + (cw.y >> 16) + 49152);
    BUF[4] = *(const unsigned*)(base1 + (cw.z & 0xFFFFu));
    BUF[5] = *(const unsigned*)(base1 + (cw.z >> 16) + 16384);
    BUF[6] = *(const unsigned*)(base1 + (cw.w & 0xFFFFu) + 32768);
    BUF[7] = *(const unsigned*)(base1 + (cw.w >> 16) + 49152);
  };

  auto consume = [&](const unsigned (&BUF)[8], const int it) {
    const unsigned M = 0x00FF00FFu;
    unsigned accA = BUF[0] & M;
    unsigned accB = (BUF[0] >> 8) & M;
#pragma unroll
    for (int j = 1; j < 8; j++) {
      accA += BUF[j] & M;
      accB += (BUF[j] >> 8) & M;
    }
    const int ss[4] = {(int)(accA & 0xFFFFu), (int)(accB & 0xFFFFu),
                       (int)(accA >> 16), (int)(accB >> 16)};
#pragma unroll
    for (int j = 0; j < 4; j++) {
      const unsigned key = ((unsigned)ss[j] << 6) | (unsigned)it;
      const unsigned mx = (k0[j] > key) ? k0[j] : key;
      k0[j] = (k0[j] < key) ? k0[j] : key;
      k1[j] = (k1[j] < mx) ? k1[j] : mx;
    }
  };

  issue(A, poffs[tid]);                 // item 0
  uint4 cJ1 = poffs[tid + 1024];        // codes for item it+1
  uint4 cJ2 = poffs[tid + 2048];        // codes for item it+2

  for (int it = 0; it < 64; it += 2) {
    const uint4 cN1 = poffs[tid + (((it + 3) & 63) << 10)];
    const uint4 cN2 = poffs[tid + (((it + 4) & 63) << 10)];
    issue(B, cJ1);
    consume(A, it);
    issue(A, cJ2);
    consume(B, it + 1);
    cJ1 = cN1; cJ2 = cN2;
  }

  // ================= SELECT PHASE (table is dead; overlay LDS) =============
  __syncthreads();   // all table reads complete before overlay writes

  unsigned* cl  = (unsigned*)dyn_lds;                       // [4][256] (d<<16)|n
  float* wts    = (float*)(dyn_lds + 4096);                 // [4][256]
  unsigned long long* sv8 = (unsigned long long*)(dyn_lds + 8192); // [4][256]
  float* gred   = (float*)(dyn_lds + 16384);                // [4][4] scratch
  unsigned* rmin = (unsigned*)(dyn_lds + 16448);            // [4]
  int* rcnt     = (int*)(dyn_lds + 16464);                  // [4]
  float* rws    = (float*)(dyn_lds + 16480);                // [4] 1/wsum

  if (tid < 4) { rmin[tid] = 0xFFFFFFFFu; rcnt[tid] = 0; }
  __syncthreads();

  // per-row quantized min
#pragma unroll
  for (int j = 0; j < 4; j++) {
    unsigned d = k0[j] >> 6;
#pragma unroll
    for (int off = 32; off > 0; off >>= 1) {
      const unsigned o = __shfl_xor(d, off);
      d = (o < d) ? o : d;
    }
    if ((tid & 63) == 0) atomicMin(&rmin[j], d);
  }
  __syncthreads();

  // ballot-compact candidates within window
  {
    const int lane = tid & 63;
    const unsigned long long lm = (1ull << lane) - 1ull;
#pragma unroll
    for (int j = 0; j < 4; j++) {
      const unsigned lim = rmin[j] + 20u;
#pragma unroll
      for (int c = 0; c < 2; c++) {
        const unsigned key = c ? k1[j] : k0[j];
        const unsigned d = key >> 6;
        const bool pred = d <= lim;
        const unsigned long long m = __ballot(pred);
        int base = 0;
        if (lane == 0 && m) base = atomicAdd(&rcnt[j], __popcll(m));
        base = __shfl(base, 0);
        if (pred) {
          const int pos = base + __popcll(m & lm);
          if (pos < 256)
            cl[j * 256 + pos] = (d << 16) | ((key & 63u) << 10) | (unsigned)tid;
        }
      }
    }
  }
  __syncthreads();

  // exact fp32 re-score (group j = tid>>8 handles row j)
  const int gj = tid >> 8, gt = tid & 255;
  const int cnt_g = min(rcnt[gj], 256);
  float dex = 1e30f;
  if (gt < cnt_g) {
    const unsigned pc = cl[gj * 256 + gt];
    const int n = (int)(pc & 0xFFFFu);
    const unsigned long long c8 = pcodes[n];
    const uint4 vc0 = *(const uint4*)&value_codes[n * 8];
    const uint4 vc1 = *(const uint4*)&value_codes[n * 8 + 4];
    sv8[gj * 256 + gt] =
        (unsigned long long)(vc0.x & 255u)        | ((unsigned long long)(vc0.y & 255u) << 8)  |
        ((unsigned long long)(vc0.z & 255u) << 16) | ((unsigned long long)(vc0.w & 255u) << 24) |
        ((unsigned long long)(vc1.x & 255u) << 32) | ((unsigned long long)(vc1.y & 255u) << 40) |
        ((unsigned long long)(vc1.z & 255u) << 48) | ((unsigned long long)(vc1.w & 255u) << 56);
    const float* lrow = lutf + ((g << 2) + gj) * 2048;
    const unsigned lo = (unsigned)c8, hi = (unsigned)(c8 >> 32);
    dex  = lrow[        (lo       & 255u)];
    dex += lrow[ 256 + ((lo >>  8) & 255u)];
    dex += lrow[ 512 + ((lo >> 16) & 255u)];
    dex += lrow[ 768 + ((lo >> 24)       )];
    dex += lrow[1024 + ( hi        & 255u)];
    dex += lrow[1280 + ((hi >>  8) & 255u)];
    dex += lrow[1536 + ((hi >> 16) & 255u)];
    dex += lrow[1792 + ((hi >> 24)       )];
  }
  // group min of dex (4 waves per group)
  float mnf = dex;
#pragma unroll
  for (int off = 32; off > 0; off >>= 1) mnf = fminf(mnf, __shfl_xor(mnf, off));
  if ((tid & 63) == 0) gred[gj * 4 + ((tid >> 6) & 3)] = mnf;
  __syncthreads();
  const float dminx = fminf(fminf(gred[gj * 4], gred[gj * 4 + 1]),
                            fminf(gred[gj * 4 + 2], gred[gj * 4 + 3]));
  const float w = (gt < cnt_g) ? __expf(dminx - dex) : 0.f;
  wts[gj * 256 + gt] = w;
  // group sum of w
  float sw_ = w;
#pragma unroll
  for (int off = 32; off > 0; off >>= 1) sw_ += __shfl_xor(sw_, off);
  __syncthreads();   // gred min-reads done; safe to overwrite
  if ((tid & 63) == 0) gred[gj * 4 + ((tid >> 6) & 3)] = sw_;
  __syncthreads();
  if (gt == 0)
    rws[gj] = 1.0f / (gred[gj * 4] + gred[gj * 4 + 1] + gred[gj * 4 + 2] + gred[gj * 4 + 3]);
  __syncthreads();

  // value gather + output: rows in pairs (h = tid>>9 selects row of pair)
  const int h = tid >> 9, u = tid & 511;
  const int col = u << 2;
  const int mv = col >> 8;
  const int co = col & 255;
  const float* vb2 = vcb + mv * 65536 + co;
  const float4 bb = *(const float4*)&bias[col];
#pragma unroll
  for (int jr = 0; jr < 2; jr++) {
    const int j = (jr << 1) | h;
    const int row = (g << 2) + j;
    const int cj = min(rcnt[j], 256);
    float4 acc = make_float4(0.f, 0.f, 0.f, 0.f);
    int k = 0;
    for (; k + 1 < cj; k += 2) {
      const float w0 = wts[j * 256 + k];
      const float w1 = wts[j * 256 + k + 1];
      const unsigned c0 = (unsigned)((sv8[j * 256 + k] >> (mv * 8)) & 255ull);
      const unsigned c1 = (unsigned)((sv8[j * 256 + k + 1] >> (mv * 8)) & 255ull);
      const float4 v0 = *(const float4*)(vb2 + c0 * 256);
      const float4 v1 = *(const float4*)(vb2 + c1 * 256);
      acc.x = fmaf(w0, v0.x, acc.x); acc.y = fmaf(w0, v0.y, acc.y);
      acc.z = fmaf(w0, v0.z, acc.z); acc.w = fmaf(w0, v0.w, acc.w);
      acc.x = fmaf(w1, v1.x, acc.x); acc.y = fmaf(w1, v1.y, acc.y);
      acc.z = fmaf(w1, v1.z, acc.z); acc.w = fmaf(w1, v1.w, acc.w);
    }
    if (k < cj) {
      const float w0 = wts[j * 256 + k];
      const unsigned c0 = (unsigned)((sv8[j * 256 + k] >> (mv * 8)) & 255ull);
      const float4 v0 = *(const float4*)(vb2 + c0 * 256);
      acc.x = fmaf(w0, v0.x, acc.x); acc.y = fmaf(w0, v0.y, acc.y);
      acc.z = fmaf(w0, v0.z, acc.z); acc.w = fmaf(w0, v0.w, acc.w);
    }
    const float iv = rws[j];
    *(float4*)&out[row * 2048 + col] =
        make_float4(fmaf(acc.x, iv, bb.x), fmaf(acc.y, iv, bb.y),
                    fmaf(acc.z, iv, bb.z), fmaf(acc.w, iv, bb.w));
  }
}

// ---------------- Kernel 3b: fallback 64KB scan (verified) ----------------
__launch_bounds__(512)
__global__ void scan16_kernel(const float* __restrict__ lut,
                              const unsigned long long* __restrict__ pcodes,
                              unsigned* __restrict__ cand_d,
                              unsigned short* __restrict__ cand_n) {
  __shared__ short sRep[32768];
  const int tid = threadIdx.x;
  const int b = blockIdx.x;

  const float4 v4 = *(const float4*)&lut[b * 2048 + tid * 4];
  float s4 = v4.x + v4.y + v4.z + v4.w;
#pragma unroll
  for (int off = 32; off > 0; off >>= 1) s4 += __shfl_xor(s4, off);
  const float mean = s4 * (1.0f / 256.0f);

  const float vals[4] = {v4.x, v4.y, v4.z, v4.w};
#pragma unroll
  for (int k2 = 0; k2 < 4; k2++) {
    float f = (vals[k2] - mean) * 64.0f;
    f = fmaxf(fminf(f, 32000.0f), -32000.0f);
    const int iv = (int)rintf(f);
    const unsigned hw = (unsigned)(unsigned short)iv;
    const unsigned wrd = hw | (hw << 16);
    const uint4 wv = make_uint4(wrd, wrd, wrd, wrd);
    const int e = tid * 4 + k2;
    *(uint4*)&((unsigned*)sRep)[e * 8] = wv;
    *(uint4*)&((unsigned*)sRep)[e * 8 + 4] = wv;
  }
  __syncthreads();

  const int r = tid & 15;
  int d0 = 0x7FFFFFFF, d1 = 0x7FFFFFFF, d2 = 0x7FFFFFFF, d3 = 0x7FFFFFFF;
  int i0 = 0, i1 = 0, i2 = 0, i3 = 0;

  unsigned long long c8 = pcodes[tid];
  for (int it = 0; it < 128; it++) {
    const int n = tid + (it << 9);
    unsigned long long nxt = 0ull;
    if (it < 127) nxt = pcodes[n + 512];
    const unsigned lo = (unsigned)c8;
    const unsigned hi = (unsigned)(c8 >> 32);
    int s;
    s  = sRep[(((lo      ) & 255u) << 4) + r        ];
    s += sRep[(((lo >>  8) & 255u) << 4) + r +  4096];
    s += sRep[(((lo >> 16) & 255u) << 4) + r +  8192];
    s += sRep[(((lo >> 24)       ) << 4) + r + 12288];
    s += sRep[(((hi      ) & 255u) << 4) + r + 16384];
    s += sRep[(((hi >>  8) & 255u) << 4) + r + 20480];
    s += sRep[(((hi >> 16) & 255u) << 4) + r + 24576];
    s += sRep[(((hi >> 24)       ) << 4) + r + 28672];
    if (s < d3) {
      if (s < d1) {
        if (s < d0) { d3 = d2; i3 = i2; d2 = d1; i2 = i1; d1 = d0; i1 = i0; d0 = s; i0 = n; }
        else        { d3 = d2; i3 = i2; d2 = d1; i2 = i1; d1 = s; i1 = n; }
      } else {
        if (s < d2) { d3 = d2; i3 = i2; d2 = s; i2 = n; }
        else        { d3 = s; i3 = n; }
      }
    }
    c8 = nxt;
  }

  const int base = b * 2048 + tid * 4;
  const uint4 dv = make_uint4((unsigned)(d0 + 0x40000000), (unsigned)(d1 + 0x40000000),
                              (unsigned)(d2 + 0x40000000), (unsigned)(d3 + 0x40000000));
  *(uint4*)&cand_d[base] = dv;
  const unsigned ni01 = (unsigned)i0 | ((unsigned)i1 << 16);
  const unsigned ni23 = (unsigned)i2 | ((unsigned)i3 << 16);
  *(uint2*)&cand_n[base] = make_uint2(ni01, ni23);
}

// ---------------- Kernel 4 (fallback path only): select + re-score ----------
__launch_bounds__(256)
__global__ void select_kernel(const unsigned* __restrict__ cand_d,
                              const unsigned short* __restrict__ cand_n,
                              const int* __restrict__ value_codes,
                              const float* __restrict__ vcb,
                              const float* __restrict__ bias,
                              const unsigned long long* __restrict__ pcodes,
                              const float* __restrict__ lutf,
                              const unsigned lim_add,
                              float* __restrict__ out) {
  __shared__ unsigned sredw[4];
  __shared__ float sredf[4];
  __shared__ unsigned long long clist[256];
  __shared__ float sw[256];
  __shared__ int svc[2048];
  __shared__ int scnt;
  __shared__ float sWsum;

  const int tid = threadIdx.x;
  const int b = blockIdx.x;

  const uint4 a0 = *(const uint4*)&cand_d[b * 2048 + tid * 8];
  const uint4 a1 = *(const uint4*)&cand_d[b * 2048 + tid * 8 + 4];
  const uint4 nn = *(const uint4*)&cand_n[b * 2048 + tid * 8];
  unsigned dk[8] = {a0.x, a0.y, a0.z, a0.w, a1.x, a1.y, a1.z, a1.w};
  unsigned ni[8] = {nn.x & 0xFFFFu, nn.x >> 16, nn.y & 0xFFFFu, nn.y >> 16,
                    nn.z & 0xFFFFu, nn.z >> 16, nn.w & 0xFFFFu, nn.w >> 16};

  if (tid == 0) scnt = 0;
  unsigned mn = dk[0];
#pragma unroll
  for (int j = 1; j < 8; j++) mn = (dk[j] < mn) ? dk[j] : mn;
#pragma unroll
  for (int off = 32; off > 0; off >>= 1) {
    const unsigned o = __shfl_xor(mn, off);
    mn = (o < mn) ? o : mn;
  }
  if ((tid & 63) == 0) sredw[tid >> 6] = mn;
  __syncthreads();
  unsigned sMin = sredw[0];
  sMin = (sredw[1] < sMin) ? sredw[1] : sMin;
  sMin = (sredw[2] < sMin) ? sredw[2] : sMin;
  sMin = (sredw[3] < sMin) ? sredw[3] : sMin;
  const unsigned lim = sMin + lim_add;

  const int lane = tid & 63;
  const unsigned long long lm = (1ull << lane) - 1ull;
#pragma unroll
  for (int j = 0; j < 8; j++) {
    const bool pred = dk[j] <= lim;
    const unsigned long long mask = __ballot(pred);
    int base = 0;
    if (lane == 0 && mask) base = atomicAdd(&scnt, __popcll(mask));
    base = __shfl(base, 0);
    if (pred) {
      const int pos = base + __popcll(mask & lm);
      if (pos < 256) clist[pos] = ((unsigned long long)dk[j] << 32) | ni[j];
    }
  }
  __syncthreads();
  const int cnt = min(scnt, 256);

  float dex = 1e30f;
  if (tid < cnt) {
    const int n = (int)(clist[tid] & 0xFFFFFFFFu);
    const unsigned long long c8 = pcodes[n];
    const float* lrow = lutf + b * 2048;
    const unsigned lo = (unsigned)c8, hi = (unsigned)(c8 >> 32);
    dex  = lrow[        (lo       & 255u)];
    dex += lrow[ 256 + ((lo >>  8) & 255u)];
    dex += lrow[ 512 + ((lo >> 16) & 255u)];
    dex += lrow[ 768 + ((lo >> 24)       )];
    dex += lrow[1024 + ( hi        & 255u)];
    dex += lrow[1280 + ((hi >>  8) & 255u)];
    dex += lrow[1536 + ((hi >> 16) & 255u)];
    dex += lrow[1792 + ((hi >> 24)       )];
  }
  for (int i = tid; i < (cnt << 3); i += 256)
    svc[i] = value_codes[((int)(clist[i >> 3] & 0xFFFFFFFFu)) * 8 + (i & 7)];
  float mnf = dex;
#pragma unroll
  for (int off = 32; off > 0; off >>= 1) mnf = fminf(mnf, __shfl_xor(mnf, off));
  if ((tid & 63) == 0) sredf[tid >> 6] = mnf;
  __syncthreads();
  const float dminx = fminf(fminf(sredf[0], sredf[1]), fminf(sredf[2], sredf[3]));
  if (tid < cnt) sw[tid] = __expf(dminx - dex);
  __syncthreads();

  if (tid < 64) {
    float s = 0.f;
    for (int j = tid; j < cnt; j += 64) s += sw[j];
#pragma unroll
    for (int off = 32; off > 0; off >>= 1) s += __shfl_xor(s, off);
    if (tid == 0) sWsum = s;
  }
  __syncthreads();
  const float inv = 1.0f / sWsum;

  const int c0 = tid << 3;
  const int mv = c0 >> 8;
  const int off = c0 & 255;
  float4 acc0 = make_float4(0.f, 0.f, 0.f, 0.f);
  float4 acc1 = make_float4(0.f, 0.f, 0.f, 0.f);
  const float* vbase = vcb + mv * 65536 + off;
  for (int k = 0; k < cnt; k++) {
    const float w = sw[k];
    const float* vp = vbase + svc[(k << 3) + mv] * 256;
    const float4 v0 = *(const float4*)vp;
    const float4 v1 = *(const float4*)(vp + 4);
    acc0.x = fmaf(w, v0.x, acc0.x); acc0.y = fmaf(w, v0.y, acc0.y);
    acc0.z = fmaf(w, v0.z, acc0.z); acc0.w = fmaf(w, v0.w, acc0.w);
    acc1.x = fmaf(w, v1.x, acc1.x); acc1.y = fmaf(w, v1.y, acc1.y);
    acc1.z = fmaf(w, v1.z, acc1.z); acc1.w = fmaf(w, v1.w, acc1.w);
  }
  const float4 b0 = *(const float4*)&bias[c0];
  const float4 b1 = *(const float4*)&bias[c0 + 4];
  *(float4*)&out[b * 2048 + c0] =
      make_float4(fmaf(acc0.x, inv, b0.x), fmaf(acc0.y, inv, b0.y),
                  fmaf(acc0.z, inv, b0.z), fmaf(acc0.w, inv, b0.w));
  *(float4*)&out[b * 2048 + c0 + 4] =
      make_float4(fmaf(acc1.x, inv, b1.x), fmaf(acc1.y, inv, b1.y),
                  fmaf(acc1.z, inv, b1.z), fmaf(acc1.w, inv, b1.w));
}

// ---------------- launch ----------------
extern "C" void kernel_launch(void* const* d_in, const int* in_sizes, int n_in,
                              void* d_out, int out_size, void* d_ws, size_t ws_size,
                              hipStream_t stream) {
  const float* x    = (const float*)d_in[0];
  const float* W    = (const float*)d_in[1];
  const float* kcb  = (const float*)d_in[2];
  const float* vcb  = (const float*)d_in[3];
  const float* bias = (const float*)d_in[4];
  const int* key_codes   = (const int*)d_in[5];
  const int* value_codes = (const int*)d_in[6];
  float* out = (float*)d_out;

  // ws: qpart 32MB | q 4MB | lut 8MB | poffs 1MB | pcodes 0.5MB | i8lut 2MB.
  // cand buffers (fallback only) alias qpart. lut live through scansel.
  float* qpart = (float*)d_ws;
  float* q     = qpart + 8388608;
  float* lut   = q + 1048576;
  uint4* poffs = (uint4*)(lut + 2097152);
  unsigned long long* pcodes = (unsigned long long*)(poffs + 65536);
  unsigned* i8lut = (unsigned*)(pcodes + 65536);
  unsigned* cand_d = (unsigned*)d_ws;
  unsigned short* cand_n = (unsigned short*)(cand_d + 2097152);

  hipLaunchKernelGGL(gemm_q_kernel, dim3(8, 8, 9), dim3(256), 0, stream,
                     x, W, key_codes, qpart, pcodes, poffs);
  hipLaunchKernelGGL(qsum_kernel, dim3(512), dim3(256), 0, stream,
                     (const float4*)qpart, (float4*)q);
  hipLaunchKernelGGL(lut_kernel, dim3(4, 16, 8), dim3(256), 0, stream,
                     q, kcb, lut, i8lut);

  const hipError_t attr_rc = hipFuncSetAttribute(
      (const void*)scansel_kernel, hipFuncAttributeMaxDynamicSharedMemorySize, 131072);
  if (attr_rc == hipSuccess) {
    hipLaunchKernelGGL(scansel_kernel, dim3(256), dim3(1024), 131072, stream,
                       lut, i8lut, poffs, pcodes, value_codes, vcb, bias, out);
  } else {
    hipLaunchKernelGGL(scan16_kernel, dim3(1024), dim3(512), 0, stream,
                       lut, pcodes, cand_d, cand_n);
    hipLaunchKernelGGL(select_kernel, dim3(1024), dim3(256), 0, stream,
                       cand_d, cand_n, value_codes, vcb, bias, pcodes, lut,
                       1024u, out);
  }
}